// Round 6
// baseline (645.427 us; speedup 1.0000x reference)
//
#include <hip/hip_runtime.h>
#include <hip/hip_fp16.h>

#define N_NODES 100000
#define N_EDGES 3200000
#define TOT_E   (N_EDGES + N_NODES)   // edges + self loops = 3,300,000
#define HEADS   4
#define DH      16
#define IN_F    300
#define HID     64
#define OUT2    32
#define SLOPE   0.2f
#define NBK     256                   // coarse buckets per list
#define GSZ     391                   // nodes per coarse bucket (256*391 >= 100000)
#define EBLK    4096                  // edges per bin block
#define NBA     ((TOT_E + EBLK - 1) / EBLK)   // 806 blocks per list

typedef _Float16 f16x8 __attribute__((ext_vector_type(8)));
typedef float    f32x4 __attribute__((ext_vector_type(4)));

// ---- W1 -> BT16[64][320] fp16 transposed, zero-padded K 300->320 ------------
__global__ void k_wcvt(const float* __restrict__ W1, __half* __restrict__ BT16) {
    int idx = blockIdx.x * 256 + threadIdx.x;
    if (idx >= HID * 320) return;
    int n = idx / 320, k = idx - n * 320;
    BT16[idx] = (k < IN_F) ? __float2half(W1[(size_t)k * HID + n]) : __float2half(0.f);
}

// ---- GEMM1 (MFMA): hH[4][N][16](fp16, head-major) = x[N,300] @ W1[300,64] ---
// 128x64 tile/block, 4 waves x (32 rows x 64 cols), BK=64 (K padded to 320).
#define G1_BM 128
#define G1_BK 64
#define G1_NS 5                       // 5*64 = 320 >= 300

__global__ __launch_bounds__(256) void k_gemm1(const float* __restrict__ x,
                                               const __half* __restrict__ BT16,
                                               __half* __restrict__ hH) {
    __shared__ _Float16 At[G1_BM][G1_BK];   // 16 KB
    __shared__ _Float16 Bt[HID][G1_BK];     // 8 KB
    const int t = threadIdx.x;
    const int lane = t & 63, w = t >> 6;
    const int lr = lane & 15, lg = lane >> 4;
    const int row0 = blockIdx.x * G1_BM;
    const int wrow = w * 32;

    int arow[4], auc[4];
    const float* axp[4];
#pragma unroll
    for (int m = 0; m < 4; m++) {
        int id = t + m * 256;
        arow[m] = id >> 3; auc[m] = id & 7;
        int gr = row0 + arow[m];
        gr = (gr < N_NODES) ? gr : (N_NODES - 1);   // clamp (stores guarded)
        axp[m] = x + (size_t)gr * IN_F + auc[m] * 8;
    }
    int bn[2], buc[2];
    const __half* bxp[2];
#pragma unroll
    for (int q = 0; q < 2; q++) {
        int id = t + q * 256;
        bn[q] = id >> 3; buc[q] = id & 7;
        bxp[q] = BT16 + bn[q] * (G1_BK * G1_NS) + buc[q] * 8;
    }

    float4 ar[4][2];
    uint4  br[2];

    auto loadS = [&](int kb) {
        if (kb + G1_BK <= IN_F) {       // full tile
#pragma unroll
            for (int m = 0; m < 4; m++) {
                ar[m][0] = *(const float4*)(axp[m] + kb);
                ar[m][1] = *(const float4*)(axp[m] + kb + 4);
            }
        } else {                        // tail tile: guard k < 300
#pragma unroll
            for (int m = 0; m < 4; m++) {
                float v[8];
#pragma unroll
                for (int e = 0; e < 8; e++) {
                    int k = kb + auc[m] * 8 + e;
                    v[e] = (k < IN_F) ? axp[m][kb + e] : 0.f;
                }
                ar[m][0] = make_float4(v[0], v[1], v[2], v[3]);
                ar[m][1] = make_float4(v[4], v[5], v[6], v[7]);
            }
        }
#pragma unroll
        for (int q = 0; q < 2; q++) br[q] = *(const uint4*)(bxp[q] + kb);
    };

    auto writeS = [&]() {
#pragma unroll
        for (int m = 0; m < 4; m++) {
            f16x8 pk;
            pk[0] = (_Float16)ar[m][0].x; pk[1] = (_Float16)ar[m][0].y;
            pk[2] = (_Float16)ar[m][0].z; pk[3] = (_Float16)ar[m][0].w;
            pk[4] = (_Float16)ar[m][1].x; pk[5] = (_Float16)ar[m][1].y;
            pk[6] = (_Float16)ar[m][1].z; pk[7] = (_Float16)ar[m][1].w;
            *(f16x8*)&At[arow[m]][(auc[m] ^ (arow[m] & 7)) << 3] = pk;
        }
#pragma unroll
        for (int q = 0; q < 2; q++)
            *(uint4*)&Bt[bn[q]][(buc[q] ^ (bn[q] & 7)) << 3] = br[q];
    };

    f32x4 acc[2][4];
#pragma unroll
    for (int mt = 0; mt < 2; mt++)
#pragma unroll
        for (int nt = 0; nt < 4; nt++) acc[mt][nt] = (f32x4){0.f, 0.f, 0.f, 0.f};

    loadS(0);
    for (int s = 0; s < G1_NS; s++) {
        __syncthreads();
        writeS();
        if (s + 1 < G1_NS) loadS((s + 1) * G1_BK);
        __syncthreads();
#pragma unroll
        for (int ks = 0; ks < 2; ks++) {
            const int u = ks * 4 + lg;
            f16x8 af[2], bf[4];
#pragma unroll
            for (int mt = 0; mt < 2; mt++) {
                int r = wrow + mt * 16 + lr;
                af[mt] = *(const f16x8*)&At[r][(u ^ (r & 7)) << 3];
            }
#pragma unroll
            for (int nt = 0; nt < 4; nt++) {
                int n = nt * 16 + lr;
                bf[nt] = *(const f16x8*)&Bt[n][(u ^ (n & 7)) << 3];
            }
#pragma unroll
            for (int mt = 0; mt < 2; mt++)
#pragma unroll
                for (int nt = 0; nt < 4; nt++)
                    acc[mt][nt] = __builtin_amdgcn_mfma_f32_16x16x32_f16(
                        af[mt], bf[nt], acc[mt][nt], 0, 0, 0);
        }
    }

    // C/D layout: col = lane&15, row = (lane>>4)*4 + reg; head = nt
#pragma unroll
    for (int mt = 0; mt < 2; mt++) {
#pragma unroll
        for (int rg = 0; rg < 4; rg++) {
            int gr = row0 + wrow + mt * 16 + lg * 4 + rg;
            if (gr < N_NODES) {
#pragma unroll
                for (int nt = 0; nt < 4; nt++)
                    hH[((size_t)nt * N_NODES + gr) * DH + lr] =
                        __float2half((float)acc[mt][nt][rg]);
            }
        }
    }
}

// ------- attention scores (head-major): asH[hd*N+n], adH[hd*N+n] -------------
__global__ void k_scores(const __half* __restrict__ hH,
                         const float* __restrict__ att_src,
                         const float* __restrict__ att_dst,
                         float* __restrict__ asH, float* __restrict__ adH) {
    int tid = blockIdx.x * blockDim.x + threadIdx.x;
    if (tid >= N_NODES * HEADS) return;
    int hd = tid / N_NODES;
    const __half* hp = &hH[(size_t)tid * DH];
    __half2 hv[8];
    *(float4*)&hv[0] = *(const float4*)hp;
    *(float4*)&hv[4] = *(const float4*)(hp + 8);
    float s = 0.f, d = 0.f;
#pragma unroll
    for (int k = 0; k < 8; k++) {
        float2 f = __half22float2(hv[k]);
        s += f.x * att_src[hd * DH + 2 * k] + f.y * att_src[hd * DH + 2 * k + 1];
        d += f.x * att_dst[hd * DH + 2 * k] + f.y * att_dst[hd * DH + 2 * k + 1];
    }
    asH[tid] = s;
    adH[tid] = d;
}

// ---------------- coarse histogram (LDS-aggregated, both lists) --------------
__global__ __launch_bounds__(512) void k_chist(const int* __restrict__ ei1,
                                               const int* __restrict__ ei2,
                                               int* __restrict__ ccnt) {
    __shared__ int hist[NBK];
    int b = blockIdx.x; const int* ei; int* cc;
    if (b < NBA) { ei = ei1; cc = ccnt; }
    else         { ei = ei2; cc = ccnt + NBK; b -= NBA; }
    int t = threadIdx.x;
    if (t < NBK) hist[t] = 0;
    __syncthreads();
    int e0 = b * EBLK;
#pragma unroll
    for (int i = 0; i < 8; i++) {
        int e = e0 + i * 512 + t;
        if (e < TOT_E) {
            int dst = (e < N_EDGES) ? ei[N_EDGES + e] : (e - N_EDGES);
            atomicAdd(&hist[(unsigned int)dst / GSZ], 1);
        }
    }
    __syncthreads();
    if (t < NBK) { int v = hist[t]; if (v) atomicAdd(&cc[t], v); }
}

// ---------------- coarse scan (1 block, 2 lists x 256) -----------------------
__global__ __launch_bounds__(512) void k_cscan(const int* __restrict__ ccnt,
                                               int* __restrict__ crp,
                                               int* __restrict__ ccur) {
    __shared__ int sc[512];
    int t = threadIdx.x;
    int idx = t & (NBK - 1);
    int own = ccnt[t];
    sc[t] = own;
    __syncthreads();
    for (int off = 1; off < NBK; off <<= 1) {
        int v = (idx >= off) ? sc[t - off] : 0;
        __syncthreads();
        sc[t] += v;
        __syncthreads();
    }
    int ex = sc[t] - own;
    crp[t] = ex; ccur[t] = ex;
}

// ---------------- coarse bin: scatter packed (dst_lo<<17 | src) --------------
__global__ __launch_bounds__(512) void k_binA(const int* __restrict__ ei1,
                                              const int* __restrict__ ei2,
                                              int* __restrict__ ccur,
                                              unsigned int* __restrict__ tmp) {
    __shared__ int hist[NBK];
    __shared__ int base[NBK];
    int b = blockIdx.x; const int* ei; int loff;
    if (b < NBA) { ei = ei1; loff = 0; }
    else         { ei = ei2; loff = 1; b -= NBA; }
    int t = threadIdx.x;
    if (t < NBK) hist[t] = 0;
    __syncthreads();
    unsigned int pk[8]; int cb[8], rk[8];
    int e0 = b * EBLK;
#pragma unroll
    for (int i = 0; i < 8; i++) {
        int e = e0 + i * 512 + t;
        cb[i] = -1;
        if (e < TOT_E) {
            int src, dst;
            if (e < N_EDGES) { src = ei[e]; dst = ei[N_EDGES + e]; }
            else             { src = e - N_EDGES; dst = src; }
            unsigned int c   = (unsigned int)dst / GSZ;
            unsigned int dlo = (unsigned int)dst - c * GSZ;
            cb[i] = (int)c;
            pk[i] = (dlo << 17) | (unsigned int)src;
            rk[i] = atomicAdd(&hist[c], 1);
        }
    }
    __syncthreads();
    if (t < NBK) {
        int v = hist[t];
        base[t] = v ? atomicAdd(&ccur[loff * NBK + t], v) : 0;
    }
    __syncthreads();
    unsigned int* tp = tmp + (size_t)loff * TOT_E;
#pragma unroll
    for (int i = 0; i < 8; i++)
        if (cb[i] >= 0) tp[base[cb[i]] + rk[i]] = pk[i];
}

// ---------------- local bin: fine hist+scan+rowptr+dinv+scatter --------------
__global__ __launch_bounds__(256) void k_binB(const unsigned int* __restrict__ tmp,
                                              const int* __restrict__ crp,
                                              int* __restrict__ rowptr,
                                              int* __restrict__ srcs,
                                              float* __restrict__ dinv) {
    __shared__ int cnt[GSZ + 1];
    __shared__ int sc[512];
    __shared__ int cur[GSZ + 1];
    int blk = blockIdx.x;
    int l = blk >> 8, b = blk & 255;
    int t = threadIdx.x;
    int nbeg = b * GSZ;
    int ncnt = min(GSZ, N_NODES - nbeg);
    const int* crpl = crp + l * NBK;
    int ebeg = crpl[b];
    int eend = (b < NBK - 1) ? crpl[b + 1] : TOT_E;
    const unsigned int* tp = tmp + (size_t)l * TOT_E;
    for (int i = t; i < GSZ + 1; i += 256) cnt[i] = 0;
    __syncthreads();
    for (int e = ebeg + t; e < eend; e += 256)
        atomicAdd(&cnt[tp[e] >> 17], 1);
    __syncthreads();
    int t2 = t + 256;
    sc[t]  = (t  < ncnt) ? cnt[t]  : 0;
    sc[t2] = (t2 < ncnt) ? cnt[t2] : 0;
    __syncthreads();
    for (int off = 1; off < 512; off <<= 1) {
        int v0 = (t  >= off) ? sc[t  - off] : 0;
        int v1 = (t2 >= off) ? sc[t2 - off] : 0;
        __syncthreads();
        sc[t] += v0; sc[t2] += v1;
        __syncthreads();
    }
    for (int i = t; i < ncnt; i += 256) {
        int c = cnt[i];
        int gpos = ebeg + sc[i] - c;   // exclusive
        rowptr[l * N_NODES + nbeg + i] = gpos;
        cur[i] = gpos;
        if (l == 1) dinv[nbeg + i] = rsqrtf((float)c);   // c >= 1 (self-loop)
    }
    __syncthreads();
    int* so = srcs + (size_t)l * TOT_E;
    for (int e = ebeg + t; e < eend; e += 256) {
        unsigned int p = tp[e];
        int pos = atomicAdd(&cur[p >> 17], 1);
        so[pos] = (int)(p & 0x1FFFF);
    }
}

// ---- GAT aggregation: 4 per-head passes (head-outer grid, L2-resident) ------
// 16-lane group per dst: 8 edge-slots x 2 half-row lanes (16 B each).
// Per-head working set = hH slice 3.2 MB + asH slice 0.4 MB < 4 MB XCD L2.
#define GAT_BPH (N_NODES / 16)   // 6250 blocks per head

__global__ __launch_bounds__(256) void k_gat(const __half* __restrict__ hH,
                                             const float* __restrict__ asH,
                                             const float* __restrict__ adH,
                                             const int* __restrict__ rowptr,
                                             const int* __restrict__ srcs,
                                             const float* __restrict__ b1,
                                             float* __restrict__ x1) {
    int bid = blockIdx.x;
    int hd = bid / GAT_BPH;
    int blk = bid - hd * GAT_BPH;
    int w = blk * 16 + (threadIdx.x >> 4);   // dst node (always < N)
    int lane = threadIdx.x & 15;
    int eidx = lane >> 1;                    // edge slot 0..7
    int c0 = (lane & 1) * 8;                 // half-row offset (halves)
    const __half* hT = hH + (size_t)hd * N_NODES * DH;
    const float* asT = asH + (size_t)hd * N_NODES;
    float ad = adH[(size_t)hd * N_NODES + w];
    int beg = rowptr[w];
    int end = (w == N_NODES - 1) ? TOT_E : rowptr[w + 1];
    float l = 0.f;
    float a0 = 0.f, a1 = 0.f, a2 = 0.f, a3 = 0.f;
    float a4 = 0.f, a5 = 0.f, a6 = 0.f, a7 = 0.f;
#pragma unroll 2
    for (int j = beg; j < end; j += 8) {
        int je = j + eidx;
        int s = __builtin_nontemporal_load(&srcs[min(je, end - 1)]);
        uint4 raw = *(const uint4*)&hT[(size_t)s * DH + c0];
        float e = asT[s] + ad;
        e = fminf(fmaxf(e, SLOPE * e), 60.f);
        float p = (je < end) ? __expf(e) : 0.f;
        l += p;
        const __half2* hv = (const __half2*)&raw;
        float2 f0 = __half22float2(hv[0]);
        float2 f1 = __half22float2(hv[1]);
        float2 f2 = __half22float2(hv[2]);
        float2 f3 = __half22float2(hv[3]);
        a0 += p * f0.x; a1 += p * f0.y; a2 += p * f1.x; a3 += p * f1.y;
        a4 += p * f2.x; a5 += p * f2.y; a6 += p * f3.x; a7 += p * f3.y;
    }
    // reduce across the 8 edge slots (lane bits 1,2,3) — stays in 16-lane group
    l  += __shfl_xor(l, 2, 64);  l  += __shfl_xor(l, 4, 64);  l  += __shfl_xor(l, 8, 64);
    a0 += __shfl_xor(a0, 2, 64); a0 += __shfl_xor(a0, 4, 64); a0 += __shfl_xor(a0, 8, 64);
    a1 += __shfl_xor(a1, 2, 64); a1 += __shfl_xor(a1, 4, 64); a1 += __shfl_xor(a1, 8, 64);
    a2 += __shfl_xor(a2, 2, 64); a2 += __shfl_xor(a2, 4, 64); a2 += __shfl_xor(a2, 8, 64);
    a3 += __shfl_xor(a3, 2, 64); a3 += __shfl_xor(a3, 4, 64); a3 += __shfl_xor(a3, 8, 64);
    a4 += __shfl_xor(a4, 2, 64); a4 += __shfl_xor(a4, 4, 64); a4 += __shfl_xor(a4, 8, 64);
    a5 += __shfl_xor(a5, 2, 64); a5 += __shfl_xor(a5, 4, 64); a5 += __shfl_xor(a5, 8, 64);
    a6 += __shfl_xor(a6, 2, 64); a6 += __shfl_xor(a6, 4, 64); a6 += __shfl_xor(a6, 8, 64);
    a7 += __shfl_xor(a7, 2, 64); a7 += __shfl_xor(a7, 4, 64); a7 += __shfl_xor(a7, 8, 64);
    if (lane < 2) {   // eidx == 0; lane0 -> cols 0..7, lane1 -> cols 8..15
        float rl = 1.f / l;
        int cb = hd * DH + c0;
        float4 b0v = *(const float4*)&b1[cb];
        float4 b4v = *(const float4*)&b1[cb + 4];
        f32x4 o0 = {fmaxf(a0 * rl + b0v.x, 0.f),
                    fmaxf(a1 * rl + b0v.y, 0.f),
                    fmaxf(a2 * rl + b0v.z, 0.f),
                    fmaxf(a3 * rl + b0v.w, 0.f)};
        f32x4 o4 = {fmaxf(a4 * rl + b4v.x, 0.f),
                    fmaxf(a5 * rl + b4v.y, 0.f),
                    fmaxf(a6 * rl + b4v.z, 0.f),
                    fmaxf(a7 * rl + b4v.w, 0.f)};
        __builtin_nontemporal_store(o0, (f32x4*)&x1[(size_t)w * HID + cb]);
        __builtin_nontemporal_store(o4, (f32x4*)&x1[(size_t)w * HID + cb + 4]);
    }
}

// ------- GEMM2: h2s16[N,32](fp16) = (x1[N,64] @ W2[64,32]) * dinv[row] -------
__global__ __launch_bounds__(256) void k_gemm2(const float* __restrict__ x1,
                                               const float* __restrict__ W2,
                                               const float* __restrict__ dinv,
                                               __half* __restrict__ h2s) {
    __shared__ float wl[HID * OUT2];   // 8 KB
    __shared__ float xl[8][HID];       // 2 KB
    int t = threadIdx.x;
    for (int i = t; i < HID * OUT2; i += 256) wl[i] = W2[i];
    int row0 = blockIdx.x * 8;
    for (int i = t; i < 8 * HID; i += 256) {
        int rr = i >> 6, kk = i & 63;
        int gr = row0 + rr;
        xl[rr][kk] = (gr < N_NODES) ? x1[(size_t)gr * HID + kk] : 0.f;
    }
    __syncthreads();
    int r = t >> 5, c = t & 31;
    float acc = 0.f;
#pragma unroll 8
    for (int k = 0; k < HID; k++) acc += xl[r][k] * wl[k * OUT2 + c];
    int gr = row0 + r;
    if (gr < N_NODES) h2s[(size_t)gr * OUT2 + c] = __float2half(acc * dinv[gr]);
}

// ---- GCN aggregation: wave/dst, lane = edge-slot(16) x col-octet(4) ---------
__global__ __launch_bounds__(256) void k_gcn(const __half* __restrict__ h2s,
                                             const float* __restrict__ dinv,
                                             const int* __restrict__ rowptr,
                                             const int* __restrict__ srcs,
                                             const float* __restrict__ b2,
                                             float* __restrict__ out) {
    int w = (blockIdx.x * 256 + threadIdx.x) >> 6;
    if (w >= N_NODES) return;
    int lane = threadIdx.x & 63;
    int eidx = lane >> 2;          // edge slot 0..15
    int cq = lane & 3;             // column octet 0..3
    int c0 = cq * 8;               // half-col offset
    int beg = rowptr[w];
    int end = (w == N_NODES - 1) ? TOT_E : rowptr[w + 1];
    float a0 = 0.f, a1 = 0.f, a2 = 0.f, a3 = 0.f;
    float a4 = 0.f, a5 = 0.f, a6 = 0.f, a7 = 0.f;
#pragma unroll 2
    for (int j = beg; j < end; j += 16) {
        int je = j + eidx;
        int s = __builtin_nontemporal_load(&srcs[min(je, end - 1)]);
        uint4 raw = *(const uint4*)&h2s[(size_t)s * OUT2 + c0];
        if (je < end) {
            const __half2* hv = (const __half2*)&raw;
            float2 f0 = __half22float2(hv[0]);
            float2 f1 = __half22float2(hv[1]);
            float2 f2 = __half22float2(hv[2]);
            float2 f3 = __half22float2(hv[3]);
            a0 += f0.x; a1 += f0.y; a2 += f1.x; a3 += f1.y;
            a4 += f2.x; a5 += f2.y; a6 += f3.x; a7 += f3.y;
        }
    }
    a0 += __shfl_xor(a0, 4, 64); a0 += __shfl_xor(a0, 8, 64); a0 += __shfl_xor(a0, 16, 64); a0 += __shfl_xor(a0, 32, 64);
    a1 += __shfl_xor(a1, 4, 64); a1 += __shfl_xor(a1, 8, 64); a1 += __shfl_xor(a1, 16, 64); a1 += __shfl_xor(a1, 32, 64);
    a2 += __shfl_xor(a2, 4, 64); a2 += __shfl_xor(a2, 8, 64); a2 += __shfl_xor(a2, 16, 64); a2 += __shfl_xor(a2, 32, 64);
    a3 += __shfl_xor(a3, 4, 64); a3 += __shfl_xor(a3, 8, 64); a3 += __shfl_xor(a3, 16, 64); a3 += __shfl_xor(a3, 32, 64);
    a4 += __shfl_xor(a4, 4, 64); a4 += __shfl_xor(a4, 8, 64); a4 += __shfl_xor(a4, 16, 64); a4 += __shfl_xor(a4, 32, 64);
    a5 += __shfl_xor(a5, 4, 64); a5 += __shfl_xor(a5, 8, 64); a5 += __shfl_xor(a5, 16, 64); a5 += __shfl_xor(a5, 32, 64);
    a6 += __shfl_xor(a6, 4, 64); a6 += __shfl_xor(a6, 8, 64); a6 += __shfl_xor(a6, 16, 64); a6 += __shfl_xor(a6, 32, 64);
    a7 += __shfl_xor(a7, 4, 64); a7 += __shfl_xor(a7, 8, 64); a7 += __shfl_xor(a7, 16, 64); a7 += __shfl_xor(a7, 32, 64);
    if (eidx == 0) {
        float dv = dinv[w];
        float4 b0 = *(const float4*)&b2[c0];
        float4 b4 = *(const float4*)&b2[c0 + 4];
        float4 o0 = make_float4(a0 * dv + b0.x, a1 * dv + b0.y,
                                a2 * dv + b0.z, a3 * dv + b0.w);
        float4 o4 = make_float4(a4 * dv + b4.x, a5 * dv + b4.y,
                                a6 * dv + b4.z, a7 * dv + b4.w);
        *(float4*)&out[(size_t)w * OUT2 + c0] = o0;
        *(float4*)&out[(size_t)w * OUT2 + c0 + 4] = o4;
    }
}

// ---------------- launch -----------------------------------------------------
static inline size_t align_up(size_t v, size_t a) { return (v + a - 1) & ~(a - 1); }

extern "C" void kernel_launch(void* const* d_in, const int* in_sizes, int n_in,
                              void* d_out, int out_size, void* d_ws, size_t ws_size,
                              hipStream_t stream) {
    const float* x       = (const float*)d_in[0];
    const float* W1      = (const float*)d_in[1];
    const float* att_src = (const float*)d_in[2];
    const float* att_dst = (const float*)d_in[3];
    const float* b1      = (const float*)d_in[4];
    const float* W2      = (const float*)d_in[5];
    const float* b2      = (const float*)d_in[6];
    const int*   ei1     = (const int*)d_in[7];
    const int*   ei2     = (const int*)d_in[8];
    float* out = (float*)d_out;

    char* p = (char*)d_ws;
    size_t off = 0;
    auto carve = [&](size_t bytes) { void* q = p + off; off = align_up(off + bytes, 256); return q; };
    __half* hH    = (__half*)carve((size_t)HEADS * N_NODES * DH * 2); // 12.8 MB head-major
    float* x1     = (float*)carve((size_t)N_NODES * HID * 4);    // 25.6 MB
    __half* h2s   = (__half*)carve((size_t)N_NODES * OUT2 * 2);  // 6.4 MB
    float* asH    = (float*)carve((size_t)HEADS * N_NODES * 4);  // 1.6 MB
    float* adH    = (float*)carve((size_t)HEADS * N_NODES * 4);  // 1.6 MB
    float* dinv   = (float*)carve((size_t)N_NODES * 4);          // 0.4 MB
    int* rowptr   = (int*)carve((size_t)2 * N_NODES * 4);        // 0.8 MB
    int* srcs     = (int*)carve((size_t)2 * TOT_E * 4);          // 26.4 MB
    int* ccnt     = (int*)carve((size_t)2 * NBK * 4);
    int* crp      = (int*)carve((size_t)2 * NBK * 4);
    int* ccur     = (int*)carve((size_t)2 * NBK * 4);
    __half* BT16  = (__half*)carve((size_t)HID * 320 * 2);       // 40 KB
    // tmp (26.4 MB) aliases x1(25.6)+h2s(6.4)=32 MB: both dead until after binB
    unsigned int* tmp = (unsigned int*)x1;
    (void)ws_size; (void)in_sizes; (void)n_in; (void)out_size;

    hipMemsetAsync(ccnt, 0, (size_t)2 * NBK * 4, stream);

    // dense pipeline
    k_wcvt<<<(HID * 320 + 255) / 256, 256, 0, stream>>>(W1, BT16);
    k_gemm1<<<(N_NODES + G1_BM - 1) / G1_BM, 256, 0, stream>>>(x, BT16, hH);
    k_scores<<<(N_NODES * HEADS + 255) / 256, 256, 0, stream>>>(hH, att_src, att_dst, asH, adH);

    // CSR build: coarse hist -> coarse scan -> coarse bin -> local bin
    k_chist<<<2 * NBA, 512, 0, stream>>>(ei1, ei2, ccnt);
    k_cscan<<<1, 512, 0, stream>>>(ccnt, crp, ccur);
    k_binA<<<2 * NBA, 512, 0, stream>>>(ei1, ei2, ccur, tmp);
    k_binB<<<2 * NBK, 256, 0, stream>>>(tmp, crp, rowptr, srcs, dinv);

    // GAT aggregation -> x1 (relu(+b1) fused), head-outer grid
    k_gat<<<HEADS * GAT_BPH, 256, 0, stream>>>(hH, asH, adH, rowptr, srcs, b1, x1);

    // GEMM2 -> h2s fp16 (pre-scaled by dinv[row])
    k_gemm2<<<N_NODES / 8, 256, 0, stream>>>(x1, W2, dinv, h2s);

    // GCN aggregation -> out (+b2 fused)
    k_gcn<<<N_NODES / 4, 256, 0, stream>>>(h2s, dinv, rowptr + N_NODES, srcs + TOT_E, b2, out);
}

// Round 7
// 549.036 us; speedup vs baseline: 1.1756x; 1.1756x over previous
//
#include <hip/hip_runtime.h>
#include <hip/hip_fp16.h>

#define N_NODES 100000
#define N_EDGES 3200000
#define TOT_E   (N_EDGES + N_NODES)   // edges + self loops = 3,300,000
#define HEADS   4
#define DH      16
#define IN_F    300
#define HID     64
#define OUT2    32
#define SLOPE   0.2f
#define NBK     256                   // coarse buckets per list
#define GSZ     391                   // nodes per coarse bucket (256*391 >= 100000)
#define EBLK    4096                  // edges per bin block
#define NBA     ((TOT_E + EBLK - 1) / EBLK)   // 806 blocks per list

typedef _Float16 f16x8 __attribute__((ext_vector_type(8)));
typedef float    f32x4 __attribute__((ext_vector_type(4)));

// ---- W1 -> BT16[64][320] fp16 transposed, zero-padded K 300->320 ------------
__global__ void k_wcvt(const float* __restrict__ W1, __half* __restrict__ BT16) {
    int idx = blockIdx.x * 256 + threadIdx.x;
    if (idx >= HID * 320) return;
    int n = idx / 320, k = idx - n * 320;
    BT16[idx] = (k < IN_F) ? __float2half(W1[(size_t)k * HID + n]) : __float2half(0.f);
}

// ---- GEMM1 (MFMA): h16[N,64](fp16) = x[N,300] @ W1[300,64]; scores fused ----
// 128x64 tile/block, 4 waves x (32 rows x 64 cols), BK=64 (K padded to 320).
// Epilogue: a_s/a_d reduced from f32 acc across the 16 col-lanes (4 shfl each).
#define G1_BM 128
#define G1_BK 64
#define G1_NS 5                       // 5*64 = 320 >= 300

__global__ __launch_bounds__(256) void k_gemm1(const float* __restrict__ x,
                                               const __half* __restrict__ BT16,
                                               const float* __restrict__ att_src,
                                               const float* __restrict__ att_dst,
                                               __half* __restrict__ h16,
                                               float* __restrict__ as_ad) {
    __shared__ _Float16 At[G1_BM][G1_BK];   // 16 KB
    __shared__ _Float16 Bt[HID][G1_BK];     // 8 KB
    const int t = threadIdx.x;
    const int lane = t & 63, w = t >> 6;
    const int lr = lane & 15, lg = lane >> 4;
    const int row0 = blockIdx.x * G1_BM;
    const int wrow = w * 32;

    int arow[4], auc[4];
    const float* axp[4];
#pragma unroll
    for (int m = 0; m < 4; m++) {
        int id = t + m * 256;
        arow[m] = id >> 3; auc[m] = id & 7;
        int gr = row0 + arow[m];
        gr = (gr < N_NODES) ? gr : (N_NODES - 1);   // clamp (stores guarded)
        axp[m] = x + (size_t)gr * IN_F + auc[m] * 8;
    }
    int bn[2], buc[2];
    const __half* bxp[2];
#pragma unroll
    for (int q = 0; q < 2; q++) {
        int id = t + q * 256;
        bn[q] = id >> 3; buc[q] = id & 7;
        bxp[q] = BT16 + bn[q] * (G1_BK * G1_NS) + buc[q] * 8;
    }

    float4 ar[4][2];
    uint4  br[2];

    auto loadS = [&](int kb) {
        if (kb + G1_BK <= IN_F) {       // full tile
#pragma unroll
            for (int m = 0; m < 4; m++) {
                ar[m][0] = *(const float4*)(axp[m] + kb);
                ar[m][1] = *(const float4*)(axp[m] + kb + 4);
            }
        } else {                        // tail tile: guard k < 300
#pragma unroll
            for (int m = 0; m < 4; m++) {
                float v[8];
#pragma unroll
                for (int e = 0; e < 8; e++) {
                    int k = kb + auc[m] * 8 + e;
                    v[e] = (k < IN_F) ? axp[m][kb + e] : 0.f;
                }
                ar[m][0] = make_float4(v[0], v[1], v[2], v[3]);
                ar[m][1] = make_float4(v[4], v[5], v[6], v[7]);
            }
        }
#pragma unroll
        for (int q = 0; q < 2; q++) br[q] = *(const uint4*)(bxp[q] + kb);
    };

    auto writeS = [&]() {
#pragma unroll
        for (int m = 0; m < 4; m++) {
            f16x8 pk;
            pk[0] = (_Float16)ar[m][0].x; pk[1] = (_Float16)ar[m][0].y;
            pk[2] = (_Float16)ar[m][0].z; pk[3] = (_Float16)ar[m][0].w;
            pk[4] = (_Float16)ar[m][1].x; pk[5] = (_Float16)ar[m][1].y;
            pk[6] = (_Float16)ar[m][1].z; pk[7] = (_Float16)ar[m][1].w;
            *(f16x8*)&At[arow[m]][(auc[m] ^ (arow[m] & 7)) << 3] = pk;
        }
#pragma unroll
        for (int q = 0; q < 2; q++)
            *(uint4*)&Bt[bn[q]][(buc[q] ^ (bn[q] & 7)) << 3] = br[q];
    };

    f32x4 acc[2][4];
#pragma unroll
    for (int mt = 0; mt < 2; mt++)
#pragma unroll
        for (int nt = 0; nt < 4; nt++) acc[mt][nt] = (f32x4){0.f, 0.f, 0.f, 0.f};

    loadS(0);
    for (int s = 0; s < G1_NS; s++) {
        __syncthreads();
        writeS();
        if (s + 1 < G1_NS) loadS((s + 1) * G1_BK);
        __syncthreads();
#pragma unroll
        for (int ks = 0; ks < 2; ks++) {
            const int u = ks * 4 + lg;
            f16x8 af[2], bf[4];
#pragma unroll
            for (int mt = 0; mt < 2; mt++) {
                int r = wrow + mt * 16 + lr;
                af[mt] = *(const f16x8*)&At[r][(u ^ (r & 7)) << 3];
            }
#pragma unroll
            for (int nt = 0; nt < 4; nt++) {
                int n = nt * 16 + lr;
                bf[nt] = *(const f16x8*)&Bt[n][(u ^ (n & 7)) << 3];
            }
#pragma unroll
            for (int mt = 0; mt < 2; mt++)
#pragma unroll
                for (int nt = 0; nt < 4; nt++)
                    acc[mt][nt] = __builtin_amdgcn_mfma_f32_16x16x32_f16(
                        af[mt], bf[nt], acc[mt][nt], 0, 0, 0);
        }
    }

    // per-lane attention weights for its column lr of each head nt
    float ws4[4], wd4[4];
#pragma unroll
    for (int nt = 0; nt < 4; nt++) {
        ws4[nt] = att_src[nt * DH + lr];
        wd4[nt] = att_dst[nt * DH + lr];
    }

    // C/D layout: col = lane&15, row = (lane>>4)*4 + reg; head = nt
#pragma unroll
    for (int mt = 0; mt < 2; mt++) {
#pragma unroll
        for (int rg = 0; rg < 4; rg++) {
            int gr = row0 + wrow + mt * 16 + lg * 4 + rg;
            float s_[4], d_[4];
#pragma unroll
            for (int nt = 0; nt < 4; nt++) {
                float v = (float)acc[mt][nt][rg];
                float vs = v * ws4[nt], vd = v * wd4[nt];
                vs += __shfl_xor(vs, 1, 64); vs += __shfl_xor(vs, 2, 64);
                vs += __shfl_xor(vs, 4, 64); vs += __shfl_xor(vs, 8, 64);
                vd += __shfl_xor(vd, 1, 64); vd += __shfl_xor(vd, 2, 64);
                vd += __shfl_xor(vd, 4, 64); vd += __shfl_xor(vd, 8, 64);
                s_[nt] = vs; d_[nt] = vd;
            }
            if (gr < N_NODES) {
#pragma unroll
                for (int nt = 0; nt < 4; nt++)
                    h16[(size_t)gr * HID + nt * 16 + lr] =
                        __float2half((float)acc[mt][nt][rg]);
                if (lr == 0) {
                    *(float4*)&as_ad[gr * 8] =
                        make_float4(s_[0], s_[1], s_[2], s_[3]);
                    *(float4*)&as_ad[gr * 8 + 4] =
                        make_float4(d_[0], d_[1], d_[2], d_[3]);
                }
            }
        }
    }
}

// ---------------- coarse histogram (LDS-aggregated, both lists) --------------
__global__ __launch_bounds__(512) void k_chist(const int* __restrict__ ei1,
                                               const int* __restrict__ ei2,
                                               int* __restrict__ ccnt) {
    __shared__ int hist[NBK];
    int b = blockIdx.x; const int* ei; int* cc;
    if (b < NBA) { ei = ei1; cc = ccnt; }
    else         { ei = ei2; cc = ccnt + NBK; b -= NBA; }
    int t = threadIdx.x;
    if (t < NBK) hist[t] = 0;
    __syncthreads();
    int e0 = b * EBLK;
#pragma unroll
    for (int i = 0; i < 8; i++) {
        int e = e0 + i * 512 + t;
        if (e < TOT_E) {
            int dst = (e < N_EDGES) ? ei[N_EDGES + e] : (e - N_EDGES);
            atomicAdd(&hist[(unsigned int)dst / GSZ], 1);
        }
    }
    __syncthreads();
    if (t < NBK) { int v = hist[t]; if (v) atomicAdd(&cc[t], v); }
}

// ---------------- coarse scan (1 block, 2 lists x 256) -----------------------
__global__ __launch_bounds__(512) void k_cscan(const int* __restrict__ ccnt,
                                               int* __restrict__ crp,
                                               int* __restrict__ ccur) {
    __shared__ int sc[512];
    int t = threadIdx.x;
    int idx = t & (NBK - 1);
    int own = ccnt[t];
    sc[t] = own;
    __syncthreads();
    for (int off = 1; off < NBK; off <<= 1) {
        int v = (idx >= off) ? sc[t - off] : 0;
        __syncthreads();
        sc[t] += v;
        __syncthreads();
    }
    int ex = sc[t] - own;
    crp[t] = ex; ccur[t] = ex;
}

// ---------------- coarse bin: scatter packed (dst_lo<<17 | src) --------------
__global__ __launch_bounds__(512) void k_binA(const int* __restrict__ ei1,
                                              const int* __restrict__ ei2,
                                              int* __restrict__ ccur,
                                              unsigned int* __restrict__ tmp) {
    __shared__ int hist[NBK];
    __shared__ int base[NBK];
    int b = blockIdx.x; const int* ei; int loff;
    if (b < NBA) { ei = ei1; loff = 0; }
    else         { ei = ei2; loff = 1; b -= NBA; }
    int t = threadIdx.x;
    if (t < NBK) hist[t] = 0;
    __syncthreads();
    unsigned int pk[8]; int cb[8], rk[8];
    int e0 = b * EBLK;
#pragma unroll
    for (int i = 0; i < 8; i++) {
        int e = e0 + i * 512 + t;
        cb[i] = -1;
        if (e < TOT_E) {
            int src, dst;
            if (e < N_EDGES) { src = ei[e]; dst = ei[N_EDGES + e]; }
            else             { src = e - N_EDGES; dst = src; }
            unsigned int c   = (unsigned int)dst / GSZ;
            unsigned int dlo = (unsigned int)dst - c * GSZ;
            cb[i] = (int)c;
            pk[i] = (dlo << 17) | (unsigned int)src;
            rk[i] = atomicAdd(&hist[c], 1);
        }
    }
    __syncthreads();
    if (t < NBK) {
        int v = hist[t];
        base[t] = v ? atomicAdd(&ccur[loff * NBK + t], v) : 0;
    }
    __syncthreads();
    unsigned int* tp = tmp + (size_t)loff * TOT_E;
#pragma unroll
    for (int i = 0; i < 8; i++)
        if (cb[i] >= 0) tp[base[cb[i]] + rk[i]] = pk[i];
}

// ---------------- local bin: fine hist+scan+rowptr+dinv+scatter --------------
__global__ __launch_bounds__(256) void k_binB(const unsigned int* __restrict__ tmp,
                                              const int* __restrict__ crp,
                                              int* __restrict__ rowptr,
                                              int* __restrict__ srcs,
                                              float* __restrict__ dinv) {
    __shared__ int cnt[GSZ + 1];
    __shared__ int sc[512];
    __shared__ int cur[GSZ + 1];
    int blk = blockIdx.x;
    int l = blk >> 8, b = blk & 255;
    int t = threadIdx.x;
    int nbeg = b * GSZ;
    int ncnt = min(GSZ, N_NODES - nbeg);
    const int* crpl = crp + l * NBK;
    int ebeg = crpl[b];
    int eend = (b < NBK - 1) ? crpl[b + 1] : TOT_E;
    const unsigned int* tp = tmp + (size_t)l * TOT_E;
    for (int i = t; i < GSZ + 1; i += 256) cnt[i] = 0;
    __syncthreads();
    for (int e = ebeg + t; e < eend; e += 256)
        atomicAdd(&cnt[tp[e] >> 17], 1);
    __syncthreads();
    int t2 = t + 256;
    sc[t]  = (t  < ncnt) ? cnt[t]  : 0;
    sc[t2] = (t2 < ncnt) ? cnt[t2] : 0;
    __syncthreads();
    for (int off = 1; off < 512; off <<= 1) {
        int v0 = (t  >= off) ? sc[t  - off] : 0;
        int v1 = (t2 >= off) ? sc[t2 - off] : 0;
        __syncthreads();
        sc[t] += v0; sc[t2] += v1;
        __syncthreads();
    }
    for (int i = t; i < ncnt; i += 256) {
        int c = cnt[i];
        int gpos = ebeg + sc[i] - c;   // exclusive
        rowptr[l * N_NODES + nbeg + i] = gpos;
        cur[i] = gpos;
        if (l == 1) dinv[nbeg + i] = rsqrtf((float)c);   // c >= 1 (self-loop)
    }
    __syncthreads();
    int* so = srcs + (size_t)l * TOT_E;
    for (int e = ebeg + t; e < eend; e += 256) {
        unsigned int p = tp[e];
        int pos = atomicAdd(&cur[p >> 17], 1);
        so[pos] = (int)(p & 0x1FFFF);
    }
}

// ---- GAT aggregation: wave/dst, lane = edge-slot(8) x col-octet(8) ----------
// fp16 h rows (128 B = 1 line fully consumed); x1 stored fp16 (one 16B store).
__global__ __launch_bounds__(256) void k_gat(const __half* __restrict__ h16,
                                             const float* __restrict__ as_ad,
                                             const int* __restrict__ rowptr,
                                             const int* __restrict__ srcs,
                                             const float* __restrict__ b1,
                                             __half* __restrict__ x1h) {
    int w = (blockIdx.x * 256 + threadIdx.x) >> 6;   // wave-uniform dst node
    if (w >= N_NODES) return;
    int lane = threadIdx.x & 63;
    int eidx = lane >> 3;          // edge slot 0..7
    int cl = lane & 7;             // column octet 0..7
    int hd = cl >> 1;              // single head per lane
    int c0 = cl * 8;               // column (== half) offset
    float ad = as_ad[w * 8 + 4 + hd];
    int beg = rowptr[w];
    int end = (w == N_NODES - 1) ? TOT_E : rowptr[w + 1];
    float l = 0.f;
    float a0 = 0.f, a1 = 0.f, a2 = 0.f, a3 = 0.f;
    float a4 = 0.f, a5 = 0.f, a6 = 0.f, a7 = 0.f;
#pragma unroll 2
    for (int j = beg; j < end; j += 8) {
        int je = j + eidx;
        int s = __builtin_nontemporal_load(&srcs[min(je, end - 1)]);
        uint4 raw = *(const uint4*)&h16[(size_t)s * HID + c0];
        float e = as_ad[s * 8 + hd] + ad;
        e = fminf(fmaxf(e, SLOPE * e), 60.f);
        float p = (je < end) ? __expf(e) : 0.f;
        l += p;
        const __half2* hv = (const __half2*)&raw;
        float2 f0 = __half22float2(hv[0]);
        float2 f1 = __half22float2(hv[1]);
        float2 f2 = __half22float2(hv[2]);
        float2 f3 = __half22float2(hv[3]);
        a0 += p * f0.x; a1 += p * f0.y; a2 += p * f1.x; a3 += p * f1.y;
        a4 += p * f2.x; a5 += p * f2.y; a6 += p * f3.x; a7 += p * f3.y;
    }
    // reduce across the 8 edge slots (lane bits 3,4,5)
    l  += __shfl_xor(l, 8, 64);  l  += __shfl_xor(l, 16, 64);  l  += __shfl_xor(l, 32, 64);
    a0 += __shfl_xor(a0, 8, 64); a0 += __shfl_xor(a0, 16, 64); a0 += __shfl_xor(a0, 32, 64);
    a1 += __shfl_xor(a1, 8, 64); a1 += __shfl_xor(a1, 16, 64); a1 += __shfl_xor(a1, 32, 64);
    a2 += __shfl_xor(a2, 8, 64); a2 += __shfl_xor(a2, 16, 64); a2 += __shfl_xor(a2, 32, 64);
    a3 += __shfl_xor(a3, 8, 64); a3 += __shfl_xor(a3, 16, 64); a3 += __shfl_xor(a3, 32, 64);
    a4 += __shfl_xor(a4, 8, 64); a4 += __shfl_xor(a4, 16, 64); a4 += __shfl_xor(a4, 32, 64);
    a5 += __shfl_xor(a5, 8, 64); a5 += __shfl_xor(a5, 16, 64); a5 += __shfl_xor(a5, 32, 64);
    a6 += __shfl_xor(a6, 8, 64); a6 += __shfl_xor(a6, 16, 64); a6 += __shfl_xor(a6, 32, 64);
    a7 += __shfl_xor(a7, 8, 64); a7 += __shfl_xor(a7, 16, 64); a7 += __shfl_xor(a7, 32, 64);
    if (eidx == 0) {
        float rl = 1.f / l;
        float4 b0 = *(const float4*)&b1[c0];
        float4 b4 = *(const float4*)&b1[c0 + 4];
        f16x8 o;
        o[0] = (_Float16)fmaxf(a0 * rl + b0.x, 0.f);
        o[1] = (_Float16)fmaxf(a1 * rl + b0.y, 0.f);
        o[2] = (_Float16)fmaxf(a2 * rl + b0.z, 0.f);
        o[3] = (_Float16)fmaxf(a3 * rl + b0.w, 0.f);
        o[4] = (_Float16)fmaxf(a4 * rl + b4.x, 0.f);
        o[5] = (_Float16)fmaxf(a5 * rl + b4.y, 0.f);
        o[6] = (_Float16)fmaxf(a6 * rl + b4.z, 0.f);
        o[7] = (_Float16)fmaxf(a7 * rl + b4.w, 0.f);
        *(f16x8*)&x1h[(size_t)w * HID + c0] = o;
    }
}

// --- GEMM2: h2s16[N,32](fp16) = (x1h[N,64](fp16) @ W2[64,32]) * dinv[row] ----
// 32 rows/block (exact: 3125 blocks), 4 rows/thread.
__global__ __launch_bounds__(256) void k_gemm2(const __half* __restrict__ x1h,
                                               const float* __restrict__ W2,
                                               const float* __restrict__ dinv,
                                               __half* __restrict__ h2s) {
    __shared__ float wl[HID * OUT2];   // 8 KB
    __shared__ float xl[32][HID];      // 8 KB
    int t = threadIdx.x;
    for (int i = t; i < HID * OUT2; i += 256) wl[i] = W2[i];
    int row0 = blockIdx.x * 32;
    {
        int rr = t >> 3, kk0 = (t & 7) * 8;
        uint4 raw = *(const uint4*)&x1h[(size_t)(row0 + rr) * HID + kk0];
        const __half2* hv = (const __half2*)&raw;
#pragma unroll
        for (int q = 0; q < 4; q++) {
            float2 f = __half22float2(hv[q]);
            xl[rr][kk0 + 2 * q] = f.x;
            xl[rr][kk0 + 2 * q + 1] = f.y;
        }
    }
    __syncthreads();
    int r0 = (t >> 5) * 4, c = t & 31;
    float ac0 = 0.f, ac1 = 0.f, ac2 = 0.f, ac3 = 0.f;
#pragma unroll 8
    for (int k = 0; k < HID; k++) {
        float wv = wl[k * OUT2 + c];
        ac0 += xl[r0 + 0][k] * wv;
        ac1 += xl[r0 + 1][k] * wv;
        ac2 += xl[r0 + 2][k] * wv;
        ac3 += xl[r0 + 3][k] * wv;
    }
    h2s[(size_t)(row0 + r0 + 0) * OUT2 + c] = __float2half(ac0 * dinv[row0 + r0 + 0]);
    h2s[(size_t)(row0 + r0 + 1) * OUT2 + c] = __float2half(ac1 * dinv[row0 + r0 + 1]);
    h2s[(size_t)(row0 + r0 + 2) * OUT2 + c] = __float2half(ac2 * dinv[row0 + r0 + 2]);
    h2s[(size_t)(row0 + r0 + 3) * OUT2 + c] = __float2half(ac3 * dinv[row0 + r0 + 3]);
}

// ---- GCN aggregation: wave/dst, lane = edge-slot(16) x col-octet(4) ---------
__global__ __launch_bounds__(256) void k_gcn(const __half* __restrict__ h2s,
                                             const float* __restrict__ dinv,
                                             const int* __restrict__ rowptr,
                                             const int* __restrict__ srcs,
                                             const float* __restrict__ b2,
                                             float* __restrict__ out) {
    int w = (blockIdx.x * 256 + threadIdx.x) >> 6;
    if (w >= N_NODES) return;
    int lane = threadIdx.x & 63;
    int eidx = lane >> 2;          // edge slot 0..15
    int cq = lane & 3;             // column octet 0..3
    int c0 = cq * 8;               // half-col offset
    int beg = rowptr[w];
    int end = (w == N_NODES - 1) ? TOT_E : rowptr[w + 1];
    float a0 = 0.f, a1 = 0.f, a2 = 0.f, a3 = 0.f;
    float a4 = 0.f, a5 = 0.f, a6 = 0.f, a7 = 0.f;
#pragma unroll 2
    for (int j = beg; j < end; j += 16) {
        int je = j + eidx;
        int s = __builtin_nontemporal_load(&srcs[min(je, end - 1)]);
        uint4 raw = *(const uint4*)&h2s[(size_t)s * OUT2 + c0];
        if (je < end) {
            const __half2* hv = (const __half2*)&raw;
            float2 f0 = __half22float2(hv[0]);
            float2 f1 = __half22float2(hv[1]);
            float2 f2 = __half22float2(hv[2]);
            float2 f3 = __half22float2(hv[3]);
            a0 += f0.x; a1 += f0.y; a2 += f1.x; a3 += f1.y;
            a4 += f2.x; a5 += f2.y; a6 += f3.x; a7 += f3.y;
        }
    }
    a0 += __shfl_xor(a0, 4, 64); a0 += __shfl_xor(a0, 8, 64); a0 += __shfl_xor(a0, 16, 64); a0 += __shfl_xor(a0, 32, 64);
    a1 += __shfl_xor(a1, 4, 64); a1 += __shfl_xor(a1, 8, 64); a1 += __shfl_xor(a1, 16, 64); a1 += __shfl_xor(a1, 32, 64);
    a2 += __shfl_xor(a2, 4, 64); a2 += __shfl_xor(a2, 8, 64); a2 += __shfl_xor(a2, 16, 64); a2 += __shfl_xor(a2, 32, 64);
    a3 += __shfl_xor(a3, 4, 64); a3 += __shfl_xor(a3, 8, 64); a3 += __shfl_xor(a3, 16, 64); a3 += __shfl_xor(a3, 32, 64);
    a4 += __shfl_xor(a4, 4, 64); a4 += __shfl_xor(a4, 8, 64); a4 += __shfl_xor(a4, 16, 64); a4 += __shfl_xor(a4, 32, 64);
    a5 += __shfl_xor(a5, 4, 64); a5 += __shfl_xor(a5, 8, 64); a5 += __shfl_xor(a5, 16, 64); a5 += __shfl_xor(a5, 32, 64);
    a6 += __shfl_xor(a6, 4, 64); a6 += __shfl_xor(a6, 8, 64); a6 += __shfl_xor(a6, 16, 64); a6 += __shfl_xor(a6, 32, 64);
    a7 += __shfl_xor(a7, 4, 64); a7 += __shfl_xor(a7, 8, 64); a7 += __shfl_xor(a7, 16, 64); a7 += __shfl_xor(a7, 32, 64);
    if (eidx == 0) {
        float dv = dinv[w];
        float4 b0 = *(const float4*)&b2[c0];
        float4 b4 = *(const float4*)&b2[c0 + 4];
        float4 o0 = make_float4(a0 * dv + b0.x, a1 * dv + b0.y,
                                a2 * dv + b0.z, a3 * dv + b0.w);
        float4 o4 = make_float4(a4 * dv + b4.x, a5 * dv + b4.y,
                                a6 * dv + b4.z, a7 * dv + b4.w);
        *(float4*)&out[(size_t)w * OUT2 + c0] = o0;
        *(float4*)&out[(size_t)w * OUT2 + c0 + 4] = o4;
    }
}

// ---------------- launch -----------------------------------------------------
static inline size_t align_up(size_t v, size_t a) { return (v + a - 1) & ~(a - 1); }

extern "C" void kernel_launch(void* const* d_in, const int* in_sizes, int n_in,
                              void* d_out, int out_size, void* d_ws, size_t ws_size,
                              hipStream_t stream) {
    const float* x       = (const float*)d_in[0];
    const float* W1      = (const float*)d_in[1];
    const float* att_src = (const float*)d_in[2];
    const float* att_dst = (const float*)d_in[3];
    const float* b1      = (const float*)d_in[4];
    const float* W2      = (const float*)d_in[5];
    const float* b2      = (const float*)d_in[6];
    const int*   ei1     = (const int*)d_in[7];
    const int*   ei2     = (const int*)d_in[8];
    float* out = (float*)d_out;

    char* p = (char*)d_ws;
    size_t off = 0;
    auto carve = [&](size_t bytes) { void* q = p + off; off = align_up(off + bytes, 256); return q; };
    __half* h16   = (__half*)carve((size_t)N_NODES * HID * 2);   // 12.8 MB
    __half* x1h   = (__half*)carve((size_t)N_NODES * HID * 2);   // 12.8 MB
    __half* h2s   = (__half*)carve((size_t)N_NODES * OUT2 * 2);  // 6.4 MB
    float* as_ad  = (float*)carve((size_t)N_NODES * 8 * 4);      // 3.2 MB
    float* dinv   = (float*)carve((size_t)N_NODES * 4);          // 0.4 MB
    int* rowptr   = (int*)carve((size_t)2 * N_NODES * 4);        // 0.8 MB
    int* srcs     = (int*)carve((size_t)2 * TOT_E * 4);          // 26.4 MB
    unsigned int* tmp = (unsigned int*)carve((size_t)2 * TOT_E * 4); // 26.4 MB (dedicated)
    int* ccnt     = (int*)carve((size_t)2 * NBK * 4);
    int* crp      = (int*)carve((size_t)2 * NBK * 4);
    int* ccur     = (int*)carve((size_t)2 * NBK * 4);
    __half* BT16  = (__half*)carve((size_t)HID * 320 * 2);       // 40 KB
    (void)ws_size; (void)in_sizes; (void)n_in; (void)out_size;

    hipMemsetAsync(ccnt, 0, (size_t)2 * NBK * 4, stream);

    // dense pipeline (scores fused into gemm1 epilogue)
    k_wcvt<<<(HID * 320 + 255) / 256, 256, 0, stream>>>(W1, BT16);
    k_gemm1<<<(N_NODES + G1_BM - 1) / G1_BM, 256, 0, stream>>>(x, BT16, att_src, att_dst, h16, as_ad);

    // CSR build: coarse hist -> coarse scan -> coarse bin -> local bin
    k_chist<<<2 * NBA, 512, 0, stream>>>(ei1, ei2, ccnt);
    k_cscan<<<1, 512, 0, stream>>>(ccnt, crp, ccur);
    k_binA<<<2 * NBA, 512, 0, stream>>>(ei1, ei2, ccur, tmp);
    k_binB<<<2 * NBK, 256, 0, stream>>>(tmp, crp, rowptr, srcs, dinv);

    // GAT aggregation -> x1h fp16 (relu(+b1) fused)
    k_gat<<<N_NODES / 4, 256, 0, stream>>>(h16, as_ad, rowptr, srcs, b1, x1h);

    // GEMM2 -> h2s fp16 (pre-scaled by dinv[row])
    k_gemm2<<<N_NODES / 32, 256, 0, stream>>>(x1h, W2, dinv, h2s);

    // GCN aggregation -> out (+b2 fused)
    k_gcn<<<N_NODES / 4, 256, 0, stream>>>(h2s, dinv, rowptr + N_NODES, srcs + TOT_E, b2, out);
}

// Round 8
// 544.943 us; speedup vs baseline: 1.1844x; 1.0075x over previous
//
#include <hip/hip_runtime.h>
#include <hip/hip_fp16.h>

#define N_NODES 100000
#define N_EDGES 3200000
#define TOT_E   (N_EDGES + N_NODES)   // edges + self loops = 3,300,000
#define HEADS   4
#define DH      16
#define IN_F    300
#define HID     64
#define OUT2    32
#define SLOPE   0.2f
#define NBK     512                   // coarse buckets per list
#define GSZ     196                   // nodes per coarse bucket (512*196 >= 100000)
#define EBLK    4096                  // edges per bin block
#define NBA     ((TOT_E + EBLK - 1) / EBLK)   // 806 blocks per list

typedef _Float16 f16x8 __attribute__((ext_vector_type(8)));
typedef float    f32x4 __attribute__((ext_vector_type(4)));

// ---- W1 -> BT16[64][320] fp16 transposed, zero-padded K 300->320 ------------
__global__ void k_wcvt(const float* __restrict__ W1, __half* __restrict__ BT16) {
    int idx = blockIdx.x * 256 + threadIdx.x;
    if (idx >= HID * 320) return;
    int n = idx / 320, k = idx - n * 320;
    BT16[idx] = (k < IN_F) ? __float2half(W1[(size_t)k * HID + n]) : __float2half(0.f);
}

// ---- GEMM1 (MFMA): h16[N,64](fp16) = x[N,300] @ W1[300,64]; scores fused ----
#define G1_BM 128
#define G1_BK 64
#define G1_NS 5                       // 5*64 = 320 >= 300

__global__ __launch_bounds__(256) void k_gemm1(const float* __restrict__ x,
                                               const __half* __restrict__ BT16,
                                               const float* __restrict__ att_src,
                                               const float* __restrict__ att_dst,
                                               __half* __restrict__ h16,
                                               float* __restrict__ as_ad) {
    __shared__ _Float16 At[G1_BM][G1_BK];   // 16 KB
    __shared__ _Float16 Bt[HID][G1_BK];     // 8 KB
    const int t = threadIdx.x;
    const int lane = t & 63, w = t >> 6;
    const int lr = lane & 15, lg = lane >> 4;
    const int row0 = blockIdx.x * G1_BM;
    const int wrow = w * 32;

    int arow[4], auc[4];
    const float* axp[4];
#pragma unroll
    for (int m = 0; m < 4; m++) {
        int id = t + m * 256;
        arow[m] = id >> 3; auc[m] = id & 7;
        int gr = row0 + arow[m];
        gr = (gr < N_NODES) ? gr : (N_NODES - 1);   // clamp (stores guarded)
        axp[m] = x + (size_t)gr * IN_F + auc[m] * 8;
    }
    int bn[2], buc[2];
    const __half* bxp[2];
#pragma unroll
    for (int q = 0; q < 2; q++) {
        int id = t + q * 256;
        bn[q] = id >> 3; buc[q] = id & 7;
        bxp[q] = BT16 + bn[q] * (G1_BK * G1_NS) + buc[q] * 8;
    }

    float4 ar[4][2];
    uint4  br[2];

    auto loadS = [&](int kb) {
        if (kb + G1_BK <= IN_F) {       // full tile
#pragma unroll
            for (int m = 0; m < 4; m++) {
                ar[m][0] = *(const float4*)(axp[m] + kb);
                ar[m][1] = *(const float4*)(axp[m] + kb + 4);
            }
        } else {                        // tail tile: guard k < 300
#pragma unroll
            for (int m = 0; m < 4; m++) {
                float v[8];
#pragma unroll
                for (int e = 0; e < 8; e++) {
                    int k = kb + auc[m] * 8 + e;
                    v[e] = (k < IN_F) ? axp[m][kb + e] : 0.f;
                }
                ar[m][0] = make_float4(v[0], v[1], v[2], v[3]);
                ar[m][1] = make_float4(v[4], v[5], v[6], v[7]);
            }
        }
#pragma unroll
        for (int q = 0; q < 2; q++) br[q] = *(const uint4*)(bxp[q] + kb);
    };

    auto writeS = [&]() {
#pragma unroll
        for (int m = 0; m < 4; m++) {
            f16x8 pk;
            pk[0] = (_Float16)ar[m][0].x; pk[1] = (_Float16)ar[m][0].y;
            pk[2] = (_Float16)ar[m][0].z; pk[3] = (_Float16)ar[m][0].w;
            pk[4] = (_Float16)ar[m][1].x; pk[5] = (_Float16)ar[m][1].y;
            pk[6] = (_Float16)ar[m][1].z; pk[7] = (_Float16)ar[m][1].w;
            *(f16x8*)&At[arow[m]][(auc[m] ^ (arow[m] & 7)) << 3] = pk;
        }
#pragma unroll
        for (int q = 0; q < 2; q++)
            *(uint4*)&Bt[bn[q]][(buc[q] ^ (bn[q] & 7)) << 3] = br[q];
    };

    f32x4 acc[2][4];
#pragma unroll
    for (int mt = 0; mt < 2; mt++)
#pragma unroll
        for (int nt = 0; nt < 4; nt++) acc[mt][nt] = (f32x4){0.f, 0.f, 0.f, 0.f};

    loadS(0);
    for (int s = 0; s < G1_NS; s++) {
        __syncthreads();
        writeS();
        if (s + 1 < G1_NS) loadS((s + 1) * G1_BK);
        __syncthreads();
#pragma unroll
        for (int ks = 0; ks < 2; ks++) {
            const int u = ks * 4 + lg;
            f16x8 af[2], bf[4];
#pragma unroll
            for (int mt = 0; mt < 2; mt++) {
                int r = wrow + mt * 16 + lr;
                af[mt] = *(const f16x8*)&At[r][(u ^ (r & 7)) << 3];
            }
#pragma unroll
            for (int nt = 0; nt < 4; nt++) {
                int n = nt * 16 + lr;
                bf[nt] = *(const f16x8*)&Bt[n][(u ^ (n & 7)) << 3];
            }
#pragma unroll
            for (int mt = 0; mt < 2; mt++)
#pragma unroll
                for (int nt = 0; nt < 4; nt++)
                    acc[mt][nt] = __builtin_amdgcn_mfma_f32_16x16x32_f16(
                        af[mt], bf[nt], acc[mt][nt], 0, 0, 0);
        }
    }

    // per-lane attention weights for its column lr of each head nt
    float ws4[4], wd4[4];
#pragma unroll
    for (int nt = 0; nt < 4; nt++) {
        ws4[nt] = att_src[nt * DH + lr];
        wd4[nt] = att_dst[nt * DH + lr];
    }

    // C/D layout: col = lane&15, row = (lane>>4)*4 + reg; head = nt
#pragma unroll
    for (int mt = 0; mt < 2; mt++) {
#pragma unroll
        for (int rg = 0; rg < 4; rg++) {
            int gr = row0 + wrow + mt * 16 + lg * 4 + rg;
            float s_[4], d_[4];
#pragma unroll
            for (int nt = 0; nt < 4; nt++) {
                float v = (float)acc[mt][nt][rg];
                float vs = v * ws4[nt], vd = v * wd4[nt];
                vs += __shfl_xor(vs, 1, 64); vs += __shfl_xor(vs, 2, 64);
                vs += __shfl_xor(vs, 4, 64); vs += __shfl_xor(vs, 8, 64);
                vd += __shfl_xor(vd, 1, 64); vd += __shfl_xor(vd, 2, 64);
                vd += __shfl_xor(vd, 4, 64); vd += __shfl_xor(vd, 8, 64);
                s_[nt] = vs; d_[nt] = vd;
            }
            if (gr < N_NODES) {
#pragma unroll
                for (int nt = 0; nt < 4; nt++)
                    h16[(size_t)gr * HID + nt * 16 + lr] =
                        __float2half((float)acc[mt][nt][rg]);
                if (lr == 0) {
                    *(float4*)&as_ad[gr * 8] =
                        make_float4(s_[0], s_[1], s_[2], s_[3]);
                    *(float4*)&as_ad[gr * 8 + 4] =
                        make_float4(d_[0], d_[1], d_[2], d_[3]);
                }
            }
        }
    }
}

// ---------------- coarse histogram (LDS-aggregated, both lists) --------------
__global__ __launch_bounds__(512) void k_chist(const int* __restrict__ ei1,
                                               const int* __restrict__ ei2,
                                               int* __restrict__ ccnt) {
    __shared__ int hist[NBK];
    int b = blockIdx.x; const int* ei; int* cc;
    if (b < NBA) { ei = ei1; cc = ccnt; }
    else         { ei = ei2; cc = ccnt + NBK; b -= NBA; }
    int t = threadIdx.x;
    hist[t] = 0;
    __syncthreads();
    int e0 = b * EBLK;
#pragma unroll
    for (int i = 0; i < 8; i++) {
        int e = e0 + i * 512 + t;
        if (e < TOT_E) {
            int dst = (e < N_EDGES) ? ei[N_EDGES + e] : (e - N_EDGES);
            atomicAdd(&hist[(unsigned int)dst / GSZ], 1);
        }
    }
    __syncthreads();
    { int v = hist[t]; if (v) atomicAdd(&cc[t], v); }
}

// ---------------- coarse scan (1 block, 2 lists x 512) -----------------------
__global__ __launch_bounds__(1024) void k_cscan(const int* __restrict__ ccnt,
                                                int* __restrict__ crp,
                                                int* __restrict__ ccur) {
    __shared__ int sc[1024];
    int t = threadIdx.x;
    int idx = t & (NBK - 1);
    int own = ccnt[t];
    sc[t] = own;
    __syncthreads();
    for (int off = 1; off < NBK; off <<= 1) {
        int v = (idx >= off) ? sc[t - off] : 0;
        __syncthreads();
        sc[t] += v;
        __syncthreads();
    }
    int ex = sc[t] - own;
    crp[t] = ex; ccur[t] = ex;
}

// ---------------- coarse bin: scatter packed (dst_lo<<17 | src) --------------
__global__ __launch_bounds__(512) void k_binA(const int* __restrict__ ei1,
                                              const int* __restrict__ ei2,
                                              int* __restrict__ ccur,
                                              unsigned int* __restrict__ tmp) {
    __shared__ int hist[NBK];
    __shared__ int base[NBK];
    int b = blockIdx.x; const int* ei; int loff;
    if (b < NBA) { ei = ei1; loff = 0; }
    else         { ei = ei2; loff = 1; b -= NBA; }
    int t = threadIdx.x;
    hist[t] = 0;
    __syncthreads();
    unsigned int pk[8]; int cb[8], rk[8];
    int e0 = b * EBLK;
#pragma unroll
    for (int i = 0; i < 8; i++) {
        int e = e0 + i * 512 + t;
        cb[i] = -1;
        if (e < TOT_E) {
            int src, dst;
            if (e < N_EDGES) { src = ei[e]; dst = ei[N_EDGES + e]; }
            else             { src = e - N_EDGES; dst = src; }
            unsigned int c   = (unsigned int)dst / GSZ;
            unsigned int dlo = (unsigned int)dst - c * GSZ;
            cb[i] = (int)c;
            pk[i] = (dlo << 17) | (unsigned int)src;
            rk[i] = atomicAdd(&hist[c], 1);
        }
    }
    __syncthreads();
    {
        int v = hist[t];
        base[t] = v ? atomicAdd(&ccur[loff * NBK + t], v) : 0;
    }
    __syncthreads();
    unsigned int* tp = tmp + (size_t)loff * TOT_E;
#pragma unroll
    for (int i = 0; i < 8; i++)
        if (cb[i] >= 0) tp[base[cb[i]] + rk[i]] = pk[i];
}

// ---------------- local bin: fine hist+scan+rowptr+dinv+scatter --------------
__global__ __launch_bounds__(256) void k_binB(const unsigned int* __restrict__ tmp,
                                              const int* __restrict__ crp,
                                              int* __restrict__ rowptr,
                                              int* __restrict__ srcs,
                                              float* __restrict__ dinv) {
    __shared__ int cnt[GSZ + 1];
    __shared__ int sc[256];
    __shared__ int cur[GSZ + 1];
    int blk = blockIdx.x;
    int l = blk >> 9, b = blk & (NBK - 1);
    int t = threadIdx.x;
    int nbeg = b * GSZ;
    int ncnt = min(GSZ, N_NODES - nbeg);    // may be <= 0 for last bucket
    const int* crpl = crp + l * NBK;
    int ebeg = crpl[b];
    int eend = (b < NBK - 1) ? crpl[b + 1] : TOT_E;
    const unsigned int* tp = tmp + (size_t)l * TOT_E;
    for (int i = t; i < GSZ + 1; i += 256) cnt[i] = 0;
    __syncthreads();
    for (int e = ebeg + t; e < eend; e += 256)
        atomicAdd(&cnt[tp[e] >> 17], 1);
    __syncthreads();
    sc[t] = (t < ncnt) ? cnt[t] : 0;
    __syncthreads();
    for (int off = 1; off < 256; off <<= 1) {
        int v = (t >= off) ? sc[t - off] : 0;
        __syncthreads();
        sc[t] += v;
        __syncthreads();
    }
    if (t < ncnt) {
        int c = cnt[t];
        int gpos = ebeg + sc[t] - c;   // exclusive
        rowptr[l * N_NODES + nbeg + t] = gpos;
        cur[t] = gpos;
        if (l == 1) dinv[nbeg + t] = rsqrtf((float)c);   // c >= 1 (self-loop)
    }
    __syncthreads();
    int* so = srcs + (size_t)l * TOT_E;
    for (int e = ebeg + t; e < eend; e += 256) {
        unsigned int p = tp[e];
        int pos = atomicAdd(&cur[p >> 17], 1);
        so[pos] = (int)(p & 0x1FFFF);
    }
}

// ---- GAT aggregation: wave/dst, lane = edge-slot(8) x col-octet(8) ----------
// fp16 h rows (128 B = 1 line fully consumed); x1 stored fp16 (one 16B store).
__global__ __launch_bounds__(256) void k_gat(const __half* __restrict__ h16,
                                             const float* __restrict__ as_ad,
                                             const int* __restrict__ rowptr,
                                             const int* __restrict__ srcs,
                                             const float* __restrict__ b1,
                                             __half* __restrict__ x1h) {
    int w = (blockIdx.x * 256 + threadIdx.x) >> 6;   // wave-uniform dst node
    if (w >= N_NODES) return;
    int lane = threadIdx.x & 63;
    int eidx = lane >> 3;          // edge slot 0..7
    int cl = lane & 7;             // column octet 0..7
    int hd = cl >> 1;              // single head per lane
    int c0 = cl * 8;               // column (== half) offset
    float ad = as_ad[w * 8 + 4 + hd];
    int beg = rowptr[w];
    int end = (w == N_NODES - 1) ? TOT_E : rowptr[w + 1];
    float l = 0.f;
    float a0 = 0.f, a1 = 0.f, a2 = 0.f, a3 = 0.f;
    float a4 = 0.f, a5 = 0.f, a6 = 0.f, a7 = 0.f;
#pragma unroll 4
    for (int j = beg; j < end; j += 8) {
        int je = j + eidx;
        int s = __builtin_nontemporal_load(&srcs[min(je, end - 1)]);
        uint4 raw = *(const uint4*)&h16[(size_t)s * HID + c0];
        float e = as_ad[s * 8 + hd] + ad;
        e = fminf(fmaxf(e, SLOPE * e), 60.f);
        float p = (je < end) ? __expf(e) : 0.f;
        l += p;
        const __half2* hv = (const __half2*)&raw;
        float2 f0 = __half22float2(hv[0]);
        float2 f1 = __half22float2(hv[1]);
        float2 f2 = __half22float2(hv[2]);
        float2 f3 = __half22float2(hv[3]);
        a0 += p * f0.x; a1 += p * f0.y; a2 += p * f1.x; a3 += p * f1.y;
        a4 += p * f2.x; a5 += p * f2.y; a6 += p * f3.x; a7 += p * f3.y;
    }
    // reduce across the 8 edge slots (lane bits 3,4,5)
    l  += __shfl_xor(l, 8, 64);  l  += __shfl_xor(l, 16, 64);  l  += __shfl_xor(l, 32, 64);
    a0 += __shfl_xor(a0, 8, 64); a0 += __shfl_xor(a0, 16, 64); a0 += __shfl_xor(a0, 32, 64);
    a1 += __shfl_xor(a1, 8, 64); a1 += __shfl_xor(a1, 16, 64); a1 += __shfl_xor(a1, 32, 64);
    a2 += __shfl_xor(a2, 8, 64); a2 += __shfl_xor(a2, 16, 64); a2 += __shfl_xor(a2, 32, 64);
    a3 += __shfl_xor(a3, 8, 64); a3 += __shfl_xor(a3, 16, 64); a3 += __shfl_xor(a3, 32, 64);
    a4 += __shfl_xor(a4, 8, 64); a4 += __shfl_xor(a4, 16, 64); a4 += __shfl_xor(a4, 32, 64);
    a5 += __shfl_xor(a5, 8, 64); a5 += __shfl_xor(a5, 16, 64); a5 += __shfl_xor(a5, 32, 64);
    a6 += __shfl_xor(a6, 8, 64); a6 += __shfl_xor(a6, 16, 64); a6 += __shfl_xor(a6, 32, 64);
    a7 += __shfl_xor(a7, 8, 64); a7 += __shfl_xor(a7, 16, 64); a7 += __shfl_xor(a7, 32, 64);
    if (eidx == 0) {
        float rl = 1.f / l;
        float4 b0 = *(const float4*)&b1[c0];
        float4 b4 = *(const float4*)&b1[c0 + 4];
        f16x8 o;
        o[0] = (_Float16)fmaxf(a0 * rl + b0.x, 0.f);
        o[1] = (_Float16)fmaxf(a1 * rl + b0.y, 0.f);
        o[2] = (_Float16)fmaxf(a2 * rl + b0.z, 0.f);
        o[3] = (_Float16)fmaxf(a3 * rl + b0.w, 0.f);
        o[4] = (_Float16)fmaxf(a4 * rl + b4.x, 0.f);
        o[5] = (_Float16)fmaxf(a5 * rl + b4.y, 0.f);
        o[6] = (_Float16)fmaxf(a6 * rl + b4.z, 0.f);
        o[7] = (_Float16)fmaxf(a7 * rl + b4.w, 0.f);
        *(f16x8*)&x1h[(size_t)w * HID + c0] = o;
    }
}

// --- GEMM2: h2s16[N,32](fp16) = (x1h[N,64](fp16) @ W2[64,32]) * dinv[row] ----
__global__ __launch_bounds__(256) void k_gemm2(const __half* __restrict__ x1h,
                                               const float* __restrict__ W2,
                                               const float* __restrict__ dinv,
                                               __half* __restrict__ h2s) {
    __shared__ float wl[HID * OUT2];   // 8 KB
    __shared__ float xl[32][HID];      // 8 KB
    int t = threadIdx.x;
    for (int i = t; i < HID * OUT2; i += 256) wl[i] = W2[i];
    int row0 = blockIdx.x * 32;
    {
        int rr = t >> 3, kk0 = (t & 7) * 8;
        uint4 raw = *(const uint4*)&x1h[(size_t)(row0 + rr) * HID + kk0];
        const __half2* hv = (const __half2*)&raw;
#pragma unroll
        for (int q = 0; q < 4; q++) {
            float2 f = __half22float2(hv[q]);
            xl[rr][kk0 + 2 * q] = f.x;
            xl[rr][kk0 + 2 * q + 1] = f.y;
        }
    }
    __syncthreads();
    int r0 = (t >> 5) * 4, c = t & 31;
    float ac0 = 0.f, ac1 = 0.f, ac2 = 0.f, ac3 = 0.f;
#pragma unroll 8
    for (int k = 0; k < HID; k++) {
        float wv = wl[k * OUT2 + c];
        ac0 += xl[r0 + 0][k] * wv;
        ac1 += xl[r0 + 1][k] * wv;
        ac2 += xl[r0 + 2][k] * wv;
        ac3 += xl[r0 + 3][k] * wv;
    }
    h2s[(size_t)(row0 + r0 + 0) * OUT2 + c] = __float2half(ac0 * dinv[row0 + r0 + 0]);
    h2s[(size_t)(row0 + r0 + 1) * OUT2 + c] = __float2half(ac1 * dinv[row0 + r0 + 1]);
    h2s[(size_t)(row0 + r0 + 2) * OUT2 + c] = __float2half(ac2 * dinv[row0 + r0 + 2]);
    h2s[(size_t)(row0 + r0 + 3) * OUT2 + c] = __float2half(ac3 * dinv[row0 + r0 + 3]);
}

// ---- GCN aggregation: wave/dst, lane = edge-slot(16) x col-octet(4) ---------
__global__ __launch_bounds__(256) void k_gcn(const __half* __restrict__ h2s,
                                             const float* __restrict__ dinv,
                                             const int* __restrict__ rowptr,
                                             const int* __restrict__ srcs,
                                             const float* __restrict__ b2,
                                             float* __restrict__ out) {
    int w = (blockIdx.x * 256 + threadIdx.x) >> 6;
    if (w >= N_NODES) return;
    int lane = threadIdx.x & 63;
    int eidx = lane >> 2;          // edge slot 0..15
    int cq = lane & 3;             // column octet 0..3
    int c0 = cq * 8;               // half-col offset
    int beg = rowptr[w];
    int end = (w == N_NODES - 1) ? TOT_E : rowptr[w + 1];
    float a0 = 0.f, a1 = 0.f, a2 = 0.f, a3 = 0.f;
    float a4 = 0.f, a5 = 0.f, a6 = 0.f, a7 = 0.f;
#pragma unroll 4
    for (int j = beg; j < end; j += 16) {
        int je = j + eidx;
        int s = __builtin_nontemporal_load(&srcs[min(je, end - 1)]);
        uint4 raw = *(const uint4*)&h2s[(size_t)s * OUT2 + c0];
        if (je < end) {
            const __half2* hv = (const __half2*)&raw;
            float2 f0 = __half22float2(hv[0]);
            float2 f1 = __half22float2(hv[1]);
            float2 f2 = __half22float2(hv[2]);
            float2 f3 = __half22float2(hv[3]);
            a0 += f0.x; a1 += f0.y; a2 += f1.x; a3 += f1.y;
            a4 += f2.x; a5 += f2.y; a6 += f3.x; a7 += f3.y;
        }
    }
    a0 += __shfl_xor(a0, 4, 64); a0 += __shfl_xor(a0, 8, 64); a0 += __shfl_xor(a0, 16, 64); a0 += __shfl_xor(a0, 32, 64);
    a1 += __shfl_xor(a1, 4, 64); a1 += __shfl_xor(a1, 8, 64); a1 += __shfl_xor(a1, 16, 64); a1 += __shfl_xor(a1, 32, 64);
    a2 += __shfl_xor(a2, 4, 64); a2 += __shfl_xor(a2, 8, 64); a2 += __shfl_xor(a2, 16, 64); a2 += __shfl_xor(a2, 32, 64);
    a3 += __shfl_xor(a3, 4, 64); a3 += __shfl_xor(a3, 8, 64); a3 += __shfl_xor(a3, 16, 64); a3 += __shfl_xor(a3, 32, 64);
    a4 += __shfl_xor(a4, 4, 64); a4 += __shfl_xor(a4, 8, 64); a4 += __shfl_xor(a4, 16, 64); a4 += __shfl_xor(a4, 32, 64);
    a5 += __shfl_xor(a5, 4, 64); a5 += __shfl_xor(a5, 8, 64); a5 += __shfl_xor(a5, 16, 64); a5 += __shfl_xor(a5, 32, 64);
    a6 += __shfl_xor(a6, 4, 64); a6 += __shfl_xor(a6, 8, 64); a6 += __shfl_xor(a6, 16, 64); a6 += __shfl_xor(a6, 32, 64);
    a7 += __shfl_xor(a7, 4, 64); a7 += __shfl_xor(a7, 8, 64); a7 += __shfl_xor(a7, 16, 64); a7 += __shfl_xor(a7, 32, 64);
    if (eidx == 0) {
        float dv = dinv[w];
        float4 b0 = *(const float4*)&b2[c0];
        float4 b4 = *(const float4*)&b2[c0 + 4];
        float4 o0 = make_float4(a0 * dv + b0.x, a1 * dv + b0.y,
                                a2 * dv + b0.z, a3 * dv + b0.w);
        float4 o4 = make_float4(a4 * dv + b4.x, a5 * dv + b4.y,
                                a6 * dv + b4.z, a7 * dv + b4.w);
        *(float4*)&out[(size_t)w * OUT2 + c0] = o0;
        *(float4*)&out[(size_t)w * OUT2 + c0 + 4] = o4;
    }
}

// ---------------- launch -----------------------------------------------------
static inline size_t align_up(size_t v, size_t a) { return (v + a - 1) & ~(a - 1); }

extern "C" void kernel_launch(void* const* d_in, const int* in_sizes, int n_in,
                              void* d_out, int out_size, void* d_ws, size_t ws_size,
                              hipStream_t stream) {
    const float* x       = (const float*)d_in[0];
    const float* W1      = (const float*)d_in[1];
    const float* att_src = (const float*)d_in[2];
    const float* att_dst = (const float*)d_in[3];
    const float* b1      = (const float*)d_in[4];
    const float* W2      = (const float*)d_in[5];
    const float* b2      = (const float*)d_in[6];
    const int*   ei1     = (const int*)d_in[7];
    const int*   ei2     = (const int*)d_in[8];
    float* out = (float*)d_out;

    char* p = (char*)d_ws;
    size_t off = 0;
    auto carve = [&](size_t bytes) { void* q = p + off; off = align_up(off + bytes, 256); return q; };
    __half* h16   = (__half*)carve((size_t)N_NODES * HID * 2);   // 12.8 MB
    __half* x1h   = (__half*)carve((size_t)N_NODES * HID * 2);   // 12.8 MB
    __half* h2s   = (__half*)carve((size_t)N_NODES * OUT2 * 2);  // 6.4 MB
    float* as_ad  = (float*)carve((size_t)N_NODES * 8 * 4);      // 3.2 MB
    float* dinv   = (float*)carve((size_t)N_NODES * 4);          // 0.4 MB
    int* rowptr   = (int*)carve((size_t)2 * N_NODES * 4);        // 0.8 MB
    int* srcs     = (int*)carve((size_t)2 * TOT_E * 4);          // 26.4 MB
    unsigned int* tmp = (unsigned int*)carve((size_t)2 * TOT_E * 4); // 26.4 MB (dedicated)
    int* ccnt     = (int*)carve((size_t)2 * NBK * 4);
    int* crp      = (int*)carve((size_t)2 * NBK * 4);
    int* ccur     = (int*)carve((size_t)2 * NBK * 4);
    __half* BT16  = (__half*)carve((size_t)HID * 320 * 2);       // 40 KB
    (void)ws_size; (void)in_sizes; (void)n_in; (void)out_size;

    hipMemsetAsync(ccnt, 0, (size_t)2 * NBK * 4, stream);

    // dense pipeline (scores fused into gemm1 epilogue)
    k_wcvt<<<(HID * 320 + 255) / 256, 256, 0, stream>>>(W1, BT16);
    k_gemm1<<<(N_NODES + G1_BM - 1) / G1_BM, 256, 0, stream>>>(x, BT16, att_src, att_dst, h16, as_ad);

    // CSR build: coarse hist -> coarse scan -> coarse bin -> local bin
    k_chist<<<2 * NBA, 512, 0, stream>>>(ei1, ei2, ccnt);
    k_cscan<<<1, 1024, 0, stream>>>(ccnt, crp, ccur);
    k_binA<<<2 * NBA, 512, 0, stream>>>(ei1, ei2, ccur, tmp);
    k_binB<<<2 * NBK, 256, 0, stream>>>(tmp, crp, rowptr, srcs, dinv);

    // GAT aggregation -> x1h fp16 (relu(+b1) fused)
    k_gat<<<N_NODES / 4, 256, 0, stream>>>(h16, as_ad, rowptr, srcs, b1, x1h);

    // GEMM2 -> h2s fp16 (pre-scaled by dinv[row])
    k_gemm2<<<N_NODES / 32, 256, 0, stream>>>(x1h, W2, dinv, h2s);

    // GCN aggregation -> out (+b2 fused)
    k_gcn<<<N_NODES / 4, 256, 0, stream>>>(h2s, dinv, rowptr + N_NODES, srcs + TOT_E, b2, out);
}

// Round 9
// 543.494 us; speedup vs baseline: 1.1876x; 1.0027x over previous
//
#include <hip/hip_runtime.h>
#include <hip/hip_fp16.h>

#define N_NODES 100000
#define N_EDGES 3200000
#define TOT_E   (N_EDGES + N_NODES)   // edges + self loops = 3,300,000
#define HEADS   4
#define DH      16
#define IN_F    300
#define HID     64
#define OUT2    32
#define SLOPE   0.2f
#define NBK     512                   // coarse buckets per list
#define GSZ     196                   // nodes per coarse bucket (512*196 >= 100000)
#define EBLK    4096                  // edges per bin block
#define NBA     ((TOT_E + EBLK - 1) / EBLK)   // 806 blocks per list

typedef _Float16 f16x8 __attribute__((ext_vector_type(8)));
typedef float    f32x4 __attribute__((ext_vector_type(4)));

// ---- W1 -> BT16[64][320] fp16 transposed, zero-padded K 300->320 ------------
__global__ void k_wcvt(const float* __restrict__ W1, __half* __restrict__ BT16) {
    int idx = blockIdx.x * 256 + threadIdx.x;
    if (idx >= HID * 320) return;
    int n = idx / 320, k = idx - n * 320;
    BT16[idx] = (k < IN_F) ? __float2half(W1[(size_t)k * HID + n]) : __float2half(0.f);
}

// ---- GEMM1 (MFMA): h16[N,64](fp16) = x[N,300] @ W1[300,64]; scores fused ----
// BM=64 (1563 blocks, ~6 blocks/CU), 4 waves x (16 rows x 64 cols), BK=64.
// Epilogue: acc -> LDS (At reused) -> coalesced 16B h16 stores + score dots
// (one thread owns one (row,head) 32B segment; no shuffles).
#define G1_BM 64
#define G1_BK 64
#define G1_NS 5                       // 5*64 = 320 >= 300

__global__ __launch_bounds__(256) void k_gemm1(const float* __restrict__ x,
                                               const __half* __restrict__ BT16,
                                               const float* __restrict__ att_src,
                                               const float* __restrict__ att_dst,
                                               __half* __restrict__ h16,
                                               float* __restrict__ as_ad) {
    __shared__ _Float16 At[G1_BM][G1_BK];   // 8 KB (reused as output stage)
    __shared__ _Float16 Bt[HID][G1_BK];     // 8 KB
    const int t = threadIdx.x;
    const int lane = t & 63, w = t >> 6;
    const int lr = lane & 15, lg = lane >> 4;
    const int row0 = blockIdx.x * G1_BM;
    const int wrow = w * 16;

    // A-stage mapping: 2 units/thread (unit = 8 k of one row)
    int arow[2], auc[2];
    const float* axp[2];
#pragma unroll
    for (int m = 0; m < 2; m++) {
        int id = t + m * 256;
        arow[m] = id >> 3; auc[m] = id & 7;
        int gr = row0 + arow[m];
        gr = (gr < N_NODES) ? gr : (N_NODES - 1);   // clamp (stores guarded)
        axp[m] = x + (size_t)gr * IN_F + auc[m] * 8;
    }
    // B-stage mapping: 2 units/thread
    int bn[2], buc[2];
    const __half* bxp[2];
#pragma unroll
    for (int q = 0; q < 2; q++) {
        int id = t + q * 256;
        bn[q] = id >> 3; buc[q] = id & 7;
        bxp[q] = BT16 + bn[q] * (G1_BK * G1_NS) + buc[q] * 8;
    }

    float4 ar[2][2];
    uint4  br[2];

    auto loadS = [&](int kb) {
        if (kb + G1_BK <= IN_F) {       // full tile
#pragma unroll
            for (int m = 0; m < 2; m++) {
                ar[m][0] = *(const float4*)(axp[m] + kb);
                ar[m][1] = *(const float4*)(axp[m] + kb + 4);
            }
        } else {                        // tail tile: guard k < 300
#pragma unroll
            for (int m = 0; m < 2; m++) {
                float v[8];
#pragma unroll
                for (int e = 0; e < 8; e++) {
                    int k = kb + auc[m] * 8 + e;
                    v[e] = (k < IN_F) ? axp[m][kb + e] : 0.f;
                }
                ar[m][0] = make_float4(v[0], v[1], v[2], v[3]);
                ar[m][1] = make_float4(v[4], v[5], v[6], v[7]);
            }
        }
#pragma unroll
        for (int q = 0; q < 2; q++) br[q] = *(const uint4*)(bxp[q] + kb);
    };

    auto writeS = [&]() {
#pragma unroll
        for (int m = 0; m < 2; m++) {
            f16x8 pk;
            pk[0] = (_Float16)ar[m][0].x; pk[1] = (_Float16)ar[m][0].y;
            pk[2] = (_Float16)ar[m][0].z; pk[3] = (_Float16)ar[m][0].w;
            pk[4] = (_Float16)ar[m][1].x; pk[5] = (_Float16)ar[m][1].y;
            pk[6] = (_Float16)ar[m][1].z; pk[7] = (_Float16)ar[m][1].w;
            *(f16x8*)&At[arow[m]][(auc[m] ^ (arow[m] & 7)) << 3] = pk;
        }
#pragma unroll
        for (int q = 0; q < 2; q++)
            *(uint4*)&Bt[bn[q]][(buc[q] ^ (bn[q] & 7)) << 3] = br[q];
    };

    f32x4 acc[4];
#pragma unroll
    for (int nt = 0; nt < 4; nt++) acc[nt] = (f32x4){0.f, 0.f, 0.f, 0.f};

    loadS(0);
    for (int s = 0; s < G1_NS; s++) {
        __syncthreads();
        writeS();
        if (s + 1 < G1_NS) loadS((s + 1) * G1_BK);
        __syncthreads();
#pragma unroll
        for (int ks = 0; ks < 2; ks++) {
            const int u = ks * 4 + lg;
            f16x8 af, bf[4];
            {
                int r = wrow + lr;
                af = *(const f16x8*)&At[r][(u ^ (r & 7)) << 3];
            }
#pragma unroll
            for (int nt = 0; nt < 4; nt++) {
                int n = nt * 16 + lr;
                bf[nt] = *(const f16x8*)&Bt[n][(u ^ (n & 7)) << 3];
            }
#pragma unroll
            for (int nt = 0; nt < 4; nt++)
                acc[nt] = __builtin_amdgcn_mfma_f32_16x16x32_f16(
                    af, bf[nt], acc[nt], 0, 0, 0);
        }
    }

    // ---- epilogue: acc -> LDS (At dead after last compute) ----
    // C/D layout: col = lane&15, row = (lane>>4)*4 + reg; head = nt
    __syncthreads();
#pragma unroll
    for (int nt = 0; nt < 4; nt++)
#pragma unroll
        for (int rg = 0; rg < 4; rg++)
            At[wrow + lg * 4 + rg][nt * DH + lr] = (_Float16)acc[nt][rg];
    __syncthreads();

    // one thread per (row, head): coalesced h16 store + score dots
    {
        int row = t >> 2, hd = t & 3;
        int gr = row0 + row;
        f16x8 p0 = *(const f16x8*)&At[row][hd * DH];
        f16x8 p1 = *(const f16x8*)&At[row][hd * DH + 8];
        float s = 0.f, d = 0.f;
#pragma unroll
        for (int k = 0; k < 8; k++) {
            float v0 = (float)p0[k], v1 = (float)p1[k];
            s += v0 * att_src[hd * DH + k] + v1 * att_src[hd * DH + 8 + k];
            d += v0 * att_dst[hd * DH + k] + v1 * att_dst[hd * DH + 8 + k];
        }
        if (gr < N_NODES) {
            *(f16x8*)&h16[(size_t)gr * HID + hd * DH] = p0;
            *(f16x8*)&h16[(size_t)gr * HID + hd * DH + 8] = p1;
            as_ad[gr * 8 + hd] = s;
            as_ad[gr * 8 + 4 + hd] = d;
        }
    }
}

// ---------------- coarse histogram (LDS-aggregated, both lists) --------------
__global__ __launch_bounds__(512) void k_chist(const int* __restrict__ ei1,
                                               const int* __restrict__ ei2,
                                               int* __restrict__ ccnt) {
    __shared__ int hist[NBK];
    int b = blockIdx.x; const int* ei; int* cc;
    if (b < NBA) { ei = ei1; cc = ccnt; }
    else         { ei = ei2; cc = ccnt + NBK; b -= NBA; }
    int t = threadIdx.x;
    hist[t] = 0;
    __syncthreads();
    int e0 = b * EBLK;
#pragma unroll
    for (int i = 0; i < 8; i++) {
        int e = e0 + i * 512 + t;
        if (e < TOT_E) {
            int dst = (e < N_EDGES) ? ei[N_EDGES + e] : (e - N_EDGES);
            atomicAdd(&hist[(unsigned int)dst / GSZ], 1);
        }
    }
    __syncthreads();
    { int v = hist[t]; if (v) atomicAdd(&cc[t], v); }
}

// ---------------- coarse scan (1 block, 2 lists x 512) -----------------------
__global__ __launch_bounds__(1024) void k_cscan(const int* __restrict__ ccnt,
                                                int* __restrict__ crp,
                                                int* __restrict__ ccur) {
    __shared__ int sc[1024];
    int t = threadIdx.x;
    int idx = t & (NBK - 1);
    int own = ccnt[t];
    sc[t] = own;
    __syncthreads();
    for (int off = 1; off < NBK; off <<= 1) {
        int v = (idx >= off) ? sc[t - off] : 0;
        __syncthreads();
        sc[t] += v;
        __syncthreads();
    }
    int ex = sc[t] - own;
    crp[t] = ex; ccur[t] = ex;
}

// ---------------- coarse bin: scatter packed (dst_lo<<17 | src) --------------
__global__ __launch_bounds__(512) void k_binA(const int* __restrict__ ei1,
                                              const int* __restrict__ ei2,
                                              int* __restrict__ ccur,
                                              unsigned int* __restrict__ tmp) {
    __shared__ int hist[NBK];
    __shared__ int base[NBK];
    int b = blockIdx.x; const int* ei; int loff;
    if (b < NBA) { ei = ei1; loff = 0; }
    else         { ei = ei2; loff = 1; b -= NBA; }
    int t = threadIdx.x;
    hist[t] = 0;
    __syncthreads();
    unsigned int pk[8]; int cb[8], rk[8];
    int e0 = b * EBLK;
#pragma unroll
    for (int i = 0; i < 8; i++) {
        int e = e0 + i * 512 + t;
        cb[i] = -1;
        if (e < TOT_E) {
            int src, dst;
            if (e < N_EDGES) { src = ei[e]; dst = ei[N_EDGES + e]; }
            else             { src = e - N_EDGES; dst = src; }
            unsigned int c   = (unsigned int)dst / GSZ;
            unsigned int dlo = (unsigned int)dst - c * GSZ;
            cb[i] = (int)c;
            pk[i] = (dlo << 17) | (unsigned int)src;
            rk[i] = atomicAdd(&hist[c], 1);
        }
    }
    __syncthreads();
    {
        int v = hist[t];
        base[t] = v ? atomicAdd(&ccur[loff * NBK + t], v) : 0;
    }
    __syncthreads();
    unsigned int* tp = tmp + (size_t)loff * TOT_E;
#pragma unroll
    for (int i = 0; i < 8; i++)
        if (cb[i] >= 0) tp[base[cb[i]] + rk[i]] = pk[i];
}

// ---------------- local bin: fine hist+scan+rowptr+dinv+scatter --------------
__global__ __launch_bounds__(256) void k_binB(const unsigned int* __restrict__ tmp,
                                              const int* __restrict__ crp,
                                              int* __restrict__ rowptr,
                                              int* __restrict__ srcs,
                                              float* __restrict__ dinv) {
    __shared__ int cnt[GSZ + 1];
    __shared__ int sc[256];
    __shared__ int cur[GSZ + 1];
    int blk = blockIdx.x;
    int l = blk >> 9, b = blk & (NBK - 1);
    int t = threadIdx.x;
    int nbeg = b * GSZ;
    int ncnt = min(GSZ, N_NODES - nbeg);    // may be <= 0 for last bucket
    const int* crpl = crp + l * NBK;
    int ebeg = crpl[b];
    int eend = (b < NBK - 1) ? crpl[b + 1] : TOT_E;
    const unsigned int* tp = tmp + (size_t)l * TOT_E;
    for (int i = t; i < GSZ + 1; i += 256) cnt[i] = 0;
    __syncthreads();
    for (int e = ebeg + t; e < eend; e += 256)
        atomicAdd(&cnt[tp[e] >> 17], 1);
    __syncthreads();
    sc[t] = (t < ncnt) ? cnt[t] : 0;
    __syncthreads();
    for (int off = 1; off < 256; off <<= 1) {
        int v = (t >= off) ? sc[t - off] : 0;
        __syncthreads();
        sc[t] += v;
        __syncthreads();
    }
    if (t < ncnt) {
        int c = cnt[t];
        int gpos = ebeg + sc[t] - c;   // exclusive
        rowptr[l * N_NODES + nbeg + t] = gpos;
        cur[t] = gpos;
        if (l == 1) dinv[nbeg + t] = rsqrtf((float)c);   // c >= 1 (self-loop)
    }
    __syncthreads();
    int* so = srcs + (size_t)l * TOT_E;
    for (int e = ebeg + t; e < eend; e += 256) {
        unsigned int p = tp[e];
        int pos = atomicAdd(&cur[p >> 17], 1);
        so[pos] = (int)(p & 0x1FFFF);
    }
}

// ---- GAT aggregation: wave/dst, lane = edge-slot(8) x col-octet(8) ----------
// fp16 h rows (128 B = 1 line fully consumed); x1 stored fp16 (one 16B store).
__global__ __launch_bounds__(256) void k_gat(const __half* __restrict__ h16,
                                             const float* __restrict__ as_ad,
                                             const int* __restrict__ rowptr,
                                             const int* __restrict__ srcs,
                                             const float* __restrict__ b1,
                                             __half* __restrict__ x1h) {
    int w = (blockIdx.x * 256 + threadIdx.x) >> 6;   // wave-uniform dst node
    if (w >= N_NODES) return;
    int lane = threadIdx.x & 63;
    int eidx = lane >> 3;          // edge slot 0..7
    int cl = lane & 7;             // column octet 0..7
    int hd = cl >> 1;              // single head per lane
    int c0 = cl * 8;               // column (== half) offset
    float ad = as_ad[w * 8 + 4 + hd];
    int beg = rowptr[w];
    int end = (w == N_NODES - 1) ? TOT_E : rowptr[w + 1];
    float l = 0.f;
    float a0 = 0.f, a1 = 0.f, a2 = 0.f, a3 = 0.f;
    float a4 = 0.f, a5 = 0.f, a6 = 0.f, a7 = 0.f;
#pragma unroll 4
    for (int j = beg; j < end; j += 8) {
        int je = j + eidx;
        int s = __builtin_nontemporal_load(&srcs[min(je, end - 1)]);
        uint4 raw = *(const uint4*)&h16[(size_t)s * HID + c0];
        float e = as_ad[s * 8 + hd] + ad;
        e = fminf(fmaxf(e, SLOPE * e), 60.f);
        float p = (je < end) ? __expf(e) : 0.f;
        l += p;
        const __half2* hv = (const __half2*)&raw;
        float2 f0 = __half22float2(hv[0]);
        float2 f1 = __half22float2(hv[1]);
        float2 f2 = __half22float2(hv[2]);
        float2 f3 = __half22float2(hv[3]);
        a0 += p * f0.x; a1 += p * f0.y; a2 += p * f1.x; a3 += p * f1.y;
        a4 += p * f2.x; a5 += p * f2.y; a6 += p * f3.x; a7 += p * f3.y;
    }
    // reduce across the 8 edge slots (lane bits 3,4,5)
    l  += __shfl_xor(l, 8, 64);  l  += __shfl_xor(l, 16, 64);  l  += __shfl_xor(l, 32, 64);
    a0 += __shfl_xor(a0, 8, 64); a0 += __shfl_xor(a0, 16, 64); a0 += __shfl_xor(a0, 32, 64);
    a1 += __shfl_xor(a1, 8, 64); a1 += __shfl_xor(a1, 16, 64); a1 += __shfl_xor(a1, 32, 64);
    a2 += __shfl_xor(a2, 8, 64); a2 += __shfl_xor(a2, 16, 64); a2 += __shfl_xor(a2, 32, 64);
    a3 += __shfl_xor(a3, 8, 64); a3 += __shfl_xor(a3, 16, 64); a3 += __shfl_xor(a3, 32, 64);
    a4 += __shfl_xor(a4, 8, 64); a4 += __shfl_xor(a4, 16, 64); a4 += __shfl_xor(a4, 32, 64);
    a5 += __shfl_xor(a5, 8, 64); a5 += __shfl_xor(a5, 16, 64); a5 += __shfl_xor(a5, 32, 64);
    a6 += __shfl_xor(a6, 8, 64); a6 += __shfl_xor(a6, 16, 64); a6 += __shfl_xor(a6, 32, 64);
    a7 += __shfl_xor(a7, 8, 64); a7 += __shfl_xor(a7, 16, 64); a7 += __shfl_xor(a7, 32, 64);
    if (eidx == 0) {
        float rl = 1.f / l;
        float4 b0 = *(const float4*)&b1[c0];
        float4 b4 = *(const float4*)&b1[c0 + 4];
        f16x8 o;
        o[0] = (_Float16)fmaxf(a0 * rl + b0.x, 0.f);
        o[1] = (_Float16)fmaxf(a1 * rl + b0.y, 0.f);
        o[2] = (_Float16)fmaxf(a2 * rl + b0.z, 0.f);
        o[3] = (_Float16)fmaxf(a3 * rl + b0.w, 0.f);
        o[4] = (_Float16)fmaxf(a4 * rl + b4.x, 0.f);
        o[5] = (_Float16)fmaxf(a5 * rl + b4.y, 0.f);
        o[6] = (_Float16)fmaxf(a6 * rl + b4.z, 0.f);
        o[7] = (_Float16)fmaxf(a7 * rl + b4.w, 0.f);
        *(f16x8*)&x1h[(size_t)w * HID + c0] = o;
    }
}

// --- GEMM2: h2s16[N,32](fp16) = (x1h[N,64](fp16) @ W2[64,32]) * dinv[row] ----
__global__ __launch_bounds__(256) void k_gemm2(const __half* __restrict__ x1h,
                                               const float* __restrict__ W2,
                                               const float* __restrict__ dinv,
                                               __half* __restrict__ h2s) {
    __shared__ float wl[HID * OUT2];   // 8 KB
    __shared__ float xl[32][HID];      // 8 KB
    int t = threadIdx.x;
    for (int i = t; i < HID * OUT2; i += 256) wl[i] = W2[i];
    int row0 = blockIdx.x * 32;
    {
        int rr = t >> 3, kk0 = (t & 7) * 8;
        uint4 raw = *(const uint4*)&x1h[(size_t)(row0 + rr) * HID + kk0];
        const __half2* hv = (const __half2*)&raw;
#pragma unroll
        for (int q = 0; q < 4; q++) {
            float2 f = __half22float2(hv[q]);
            xl[rr][kk0 + 2 * q] = f.x;
            xl[rr][kk0 + 2 * q + 1] = f.y;
        }
    }
    __syncthreads();
    int r0 = (t >> 5) * 4, c = t & 31;
    float ac0 = 0.f, ac1 = 0.f, ac2 = 0.f, ac3 = 0.f;
#pragma unroll 8
    for (int k = 0; k < HID; k++) {
        float wv = wl[k * OUT2 + c];
        ac0 += xl[r0 + 0][k] * wv;
        ac1 += xl[r0 + 1][k] * wv;
        ac2 += xl[r0 + 2][k] * wv;
        ac3 += xl[r0 + 3][k] * wv;
    }
    h2s[(size_t)(row0 + r0 + 0) * OUT2 + c] = __float2half(ac0 * dinv[row0 + r0 + 0]);
    h2s[(size_t)(row0 + r0 + 1) * OUT2 + c] = __float2half(ac1 * dinv[row0 + r0 + 1]);
    h2s[(size_t)(row0 + r0 + 2) * OUT2 + c] = __float2half(ac2 * dinv[row0 + r0 + 2]);
    h2s[(size_t)(row0 + r0 + 3) * OUT2 + c] = __float2half(ac3 * dinv[row0 + r0 + 3]);
}

// ---- GCN aggregation: wave/dst, lane = edge-slot(16) x col-octet(4) ---------
__global__ __launch_bounds__(256) void k_gcn(const __half* __restrict__ h2s,
                                             const float* __restrict__ dinv,
                                             const int* __restrict__ rowptr,
                                             const int* __restrict__ srcs,
                                             const float* __restrict__ b2,
                                             float* __restrict__ out) {
    int w = (blockIdx.x * 256 + threadIdx.x) >> 6;
    if (w >= N_NODES) return;
    int lane = threadIdx.x & 63;
    int eidx = lane >> 2;          // edge slot 0..15
    int cq = lane & 3;             // column octet 0..3
    int c0 = cq * 8;               // half-col offset
    int beg = rowptr[w];
    int end = (w == N_NODES - 1) ? TOT_E : rowptr[w + 1];
    float a0 = 0.f, a1 = 0.f, a2 = 0.f, a3 = 0.f;
    float a4 = 0.f, a5 = 0.f, a6 = 0.f, a7 = 0.f;
#pragma unroll 4
    for (int j = beg; j < end; j += 16) {
        int je = j + eidx;
        int s = __builtin_nontemporal_load(&srcs[min(je, end - 1)]);
        uint4 raw = *(const uint4*)&h2s[(size_t)s * OUT2 + c0];
        if (je < end) {
            const __half2* hv = (const __half2*)&raw;
            float2 f0 = __half22float2(hv[0]);
            float2 f1 = __half22float2(hv[1]);
            float2 f2 = __half22float2(hv[2]);
            float2 f3 = __half22float2(hv[3]);
            a0 += f0.x; a1 += f0.y; a2 += f1.x; a3 += f1.y;
            a4 += f2.x; a5 += f2.y; a6 += f3.x; a7 += f3.y;
        }
    }
    a0 += __shfl_xor(a0, 4, 64); a0 += __shfl_xor(a0, 8, 64); a0 += __shfl_xor(a0, 16, 64); a0 += __shfl_xor(a0, 32, 64);
    a1 += __shfl_xor(a1, 4, 64); a1 += __shfl_xor(a1, 8, 64); a1 += __shfl_xor(a1, 16, 64); a1 += __shfl_xor(a1, 32, 64);
    a2 += __shfl_xor(a2, 4, 64); a2 += __shfl_xor(a2, 8, 64); a2 += __shfl_xor(a2, 16, 64); a2 += __shfl_xor(a2, 32, 64);
    a3 += __shfl_xor(a3, 4, 64); a3 += __shfl_xor(a3, 8, 64); a3 += __shfl_xor(a3, 16, 64); a3 += __shfl_xor(a3, 32, 64);
    a4 += __shfl_xor(a4, 4, 64); a4 += __shfl_xor(a4, 8, 64); a4 += __shfl_xor(a4, 16, 64); a4 += __shfl_xor(a4, 32, 64);
    a5 += __shfl_xor(a5, 4, 64); a5 += __shfl_xor(a5, 8, 64); a5 += __shfl_xor(a5, 16, 64); a5 += __shfl_xor(a5, 32, 64);
    a6 += __shfl_xor(a6, 4, 64); a6 += __shfl_xor(a6, 8, 64); a6 += __shfl_xor(a6, 16, 64); a6 += __shfl_xor(a6, 32, 64);
    a7 += __shfl_xor(a7, 4, 64); a7 += __shfl_xor(a7, 8, 64); a7 += __shfl_xor(a7, 16, 64); a7 += __shfl_xor(a7, 32, 64);
    if (eidx == 0) {
        float dv = dinv[w];
        float4 b0 = *(const float4*)&b2[c0];
        float4 b4 = *(const float4*)&b2[c0 + 4];
        float4 o0 = make_float4(a0 * dv + b0.x, a1 * dv + b0.y,
                                a2 * dv + b0.z, a3 * dv + b0.w);
        float4 o4 = make_float4(a4 * dv + b4.x, a5 * dv + b4.y,
                                a6 * dv + b4.z, a7 * dv + b4.w);
        *(float4*)&out[(size_t)w * OUT2 + c0] = o0;
        *(float4*)&out[(size_t)w * OUT2 + c0 + 4] = o4;
    }
}

// ---------------- launch -----------------------------------------------------
static inline size_t align_up(size_t v, size_t a) { return (v + a - 1) & ~(a - 1); }

extern "C" void kernel_launch(void* const* d_in, const int* in_sizes, int n_in,
                              void* d_out, int out_size, void* d_ws, size_t ws_size,
                              hipStream_t stream) {
    const float* x       = (const float*)d_in[0];
    const float* W1      = (const float*)d_in[1];
    const float* att_src = (const float*)d_in[2];
    const float* att_dst = (const float*)d_in[3];
    const float* b1      = (const float*)d_in[4];
    const float* W2      = (const float*)d_in[5];
    const float* b2      = (const float*)d_in[6];
    const int*   ei1     = (const int*)d_in[7];
    const int*   ei2     = (const int*)d_in[8];
    float* out = (float*)d_out;

    char* p = (char*)d_ws;
    size_t off = 0;
    auto carve = [&](size_t bytes) { void* q = p + off; off = align_up(off + bytes, 256); return q; };
    __half* h16   = (__half*)carve((size_t)N_NODES * HID * 2);   // 12.8 MB
    __half* x1h   = (__half*)carve((size_t)N_NODES * HID * 2);   // 12.8 MB
    __half* h2s   = (__half*)carve((size_t)N_NODES * OUT2 * 2);  // 6.4 MB
    float* as_ad  = (float*)carve((size_t)N_NODES * 8 * 4);      // 3.2 MB
    float* dinv   = (float*)carve((size_t)N_NODES * 4);          // 0.4 MB
    int* rowptr   = (int*)carve((size_t)2 * N_NODES * 4);        // 0.8 MB
    int* srcs     = (int*)carve((size_t)2 * TOT_E * 4);          // 26.4 MB
    unsigned int* tmp = (unsigned int*)carve((size_t)2 * TOT_E * 4); // 26.4 MB (dedicated)
    int* ccnt     = (int*)carve((size_t)2 * NBK * 4);
    int* crp      = (int*)carve((size_t)2 * NBK * 4);
    int* ccur     = (int*)carve((size_t)2 * NBK * 4);
    __half* BT16  = (__half*)carve((size_t)HID * 320 * 2);       // 40 KB
    (void)ws_size; (void)in_sizes; (void)n_in; (void)out_size;

    hipMemsetAsync(ccnt, 0, (size_t)2 * NBK * 4, stream);

    // dense pipeline (scores fused into gemm1 epilogue via LDS, no shuffles)
    k_wcvt<<<(HID * 320 + 255) / 256, 256, 0, stream>>>(W1, BT16);
    k_gemm1<<<(N_NODES + G1_BM - 1) / G1_BM, 256, 0, stream>>>(x, BT16, att_src, att_dst, h16, as_ad);

    // CSR build: coarse hist -> coarse scan -> coarse bin -> local bin
    k_chist<<<2 * NBA, 512, 0, stream>>>(ei1, ei2, ccnt);
    k_cscan<<<1, 1024, 0, stream>>>(ccnt, crp, ccur);
    k_binA<<<2 * NBA, 512, 0, stream>>>(ei1, ei2, ccur, tmp);
    k_binB<<<2 * NBK, 256, 0, stream>>>(tmp, crp, rowptr, srcs, dinv);

    // GAT aggregation -> x1h fp16 (relu(+b1) fused)
    k_gat<<<N_NODES / 4, 256, 0, stream>>>(h16, as_ad, rowptr, srcs, b1, x1h);

    // GEMM2 -> h2s fp16 (pre-scaled by dinv[row])
    k_gemm2<<<N_NODES / 32, 256, 0, stream>>>(x1h, W2, dinv, h2s);

    // GCN aggregation -> out (+b2 fused)
    k_gcn<<<N_NODES / 4, 256, 0, stream>>>(h2s, dinv, rowptr + N_NODES, srcs + TOT_E, b2, out);
}